// Round 7
// baseline (309.573 us; speedup 1.0000x reference)
//
#include <hip/hip_runtime.h>
#include <hip/hip_fp16.h>

#define NN 50000
#define NE 800000
#define INFEAT 128
#define F1 256
#define HID 64
#define CLS 40
#define NEGS 0.2f
#define NB 49   // ceil(NN / 1024)

__device__ __forceinline__ float lrelu(float x) { return x > 0.0f ? x : NEGS * x; }

struct alignas(8) H4 { __half2 a, b; };

// ---------------- GEMM1: fea1h = fp16(x @ W1 + b1), fused per-node scores ----------------
// 128x64 tile, 8x4 per thread -> 32 FMA per 3 LDS float4 reads per k
#define BM 128
#define BN 64
#define BK 32
__global__ __launch_bounds__(256) void gemm1_k(const float* __restrict__ A,
                                               const float* __restrict__ W,
                                               const float* __restrict__ b,
                                               const float* __restrict__ att1,
                                               __half* __restrict__ feah,
                                               float* __restrict__ sI,
                                               float* __restrict__ sJ) {
    __shared__ float As[BK][BM + 4];
    __shared__ float Bs[BK][BN];
    int tid = threadIdx.x;
    int row0 = blockIdx.x * BM;
    int head = blockIdx.y;          // BN==HID: one head per column block
    int col0 = head * BN;
    int tx = tid & 15, ty = tid >> 4;
    float acc[8][4] = {};
    for (int k0 = 0; k0 < INFEAT; k0 += BK) {
        {
            int r = tid >> 3;            // 0..31
            int c = (tid & 7) * 4;       // 0..28
            #pragma unroll
            for (int rr = r; rr < BM; rr += 32) {
                int grow = row0 + rr;
                float4 v = make_float4(0.f, 0.f, 0.f, 0.f);
                if (grow < NN) v = *(const float4*)&A[(size_t)grow * INFEAT + k0 + c];
                As[c + 0][rr] = v.x; As[c + 1][rr] = v.y;
                As[c + 2][rr] = v.z; As[c + 3][rr] = v.w;
            }
        }
        {
            int r = tid >> 4;            // 0..15
            int c = (tid & 15) * 4;
            #pragma unroll
            for (int rr = r; rr < BK; rr += 16)
                *(float4*)&Bs[rr][c] = *(const float4*)&W[(size_t)(k0 + rr) * F1 + col0 + c];
        }
        __syncthreads();
        #pragma unroll
        for (int k = 0; k < BK; ++k) {
            float4 a0 = *(const float4*)&As[k][ty * 8];
            float4 a1 = *(const float4*)&As[k][ty * 8 + 4];
            float4 bv = *(const float4*)&Bs[k][tx * 4];
            float a[8] = {a0.x, a0.y, a0.z, a0.w, a1.x, a1.y, a1.z, a1.w};
            float bb[4] = {bv.x, bv.y, bv.z, bv.w};
            #pragma unroll
            for (int i = 0; i < 8; ++i)
                #pragma unroll
                for (int j = 0; j < 4; ++j) acc[i][j] += a[i] * bb[j];
        }
        __syncthreads();
    }
    int gcol = col0 + tx * 4;
    float4 bv = *(const float4*)&b[gcol];
    float aI0 = att1[head * 2 * HID + tx * 4 + 0];
    float aI1 = att1[head * 2 * HID + tx * 4 + 1];
    float aI2 = att1[head * 2 * HID + tx * 4 + 2];
    float aI3 = att1[head * 2 * HID + tx * 4 + 3];
    float aJ0 = att1[head * 2 * HID + HID + tx * 4 + 0];
    float aJ1 = att1[head * 2 * HID + HID + tx * 4 + 1];
    float aJ2 = att1[head * 2 * HID + HID + tx * 4 + 2];
    float aJ3 = att1[head * 2 * HID + HID + tx * 4 + 3];
    float sIp[8], sJp[8];
    #pragma unroll
    for (int i = 0; i < 8; ++i) {
        float4 o = make_float4(acc[i][0] + bv.x, acc[i][1] + bv.y,
                               acc[i][2] + bv.z, acc[i][3] + bv.w);
        int grow = row0 + ty * 8 + i;
        if (grow < NN) {
            H4 v;
            v.a = __floats2half2_rn(o.x, o.y);
            v.b = __floats2half2_rn(o.z, o.w);
            *(H4*)&feah[(size_t)grow * F1 + gcol] = v;
        }
        sIp[i] = o.x * aI0 + o.y * aI1 + o.z * aI2 + o.w * aI3;
        sJp[i] = o.x * aJ0 + o.y * aJ1 + o.z * aJ2 + o.w * aJ3;
    }
    #pragma unroll
    for (int off = 1; off < 16; off <<= 1) {
        #pragma unroll
        for (int i = 0; i < 8; ++i) {
            sIp[i] += __shfl_xor(sIp[i], off);
            sJp[i] += __shfl_xor(sJp[i], off);
        }
    }
    if (tx == 0) {
        #pragma unroll
        for (int i = 0; i < 8; ++i) {
            int grow = row0 + ty * 8 + i;
            if (grow < NN) {
                sI[grow * 4 + head] = sIp[i];
                sJ[grow * 4 + head] = sJp[i];
            }
        }
    }
}

// ---------------- CSR build ----------------
__global__ void hist_k(const int* __restrict__ dst, int* __restrict__ deg) {
    int e = blockIdx.x * blockDim.x + threadIdx.x;
    if (e < NE) atomicAdd(&deg[dst[e]], 1);
}

// hierarchical scan: 49 blocks of 1024, then 1-wave scan of block sums, then add-back
__global__ __launch_bounds__(1024) void scan1_k(const int* __restrict__ deg,
                                                int* __restrict__ row_off,
                                                int* __restrict__ bsum) {
    __shared__ int tmp[1024];
    int tid = threadIdx.x;
    int gid = blockIdx.x * 1024 + tid;
    int v = (gid < NN) ? deg[gid] : 0;
    tmp[tid] = v;
    __syncthreads();
    #pragma unroll
    for (int off = 1; off < 1024; off <<= 1) {
        int t = (tid >= off) ? tmp[tid - off] : 0;
        __syncthreads();
        tmp[tid] += t;
        __syncthreads();
    }
    if (gid < NN) row_off[gid] = tmp[tid] - v;   // exclusive
    if (tid == 1023) bsum[blockIdx.x] = tmp[1023];
}

__global__ void scan2_k(const int* __restrict__ bsum, int* __restrict__ bpref) {
    int tid = threadIdx.x;           // 64 threads, one wave
    int orig = (tid < NB) ? bsum[tid] : 0;
    int v = orig;
    #pragma unroll
    for (int off = 1; off < 64; off <<= 1) {
        int t = __shfl_up(v, off);
        if (tid >= off) v += t;
    }
    if (tid < NB) bpref[tid] = v - orig;   // exclusive block prefix
}

__global__ __launch_bounds__(1024) void scan3_k(int* __restrict__ row_off,
                                                const int* __restrict__ bpref) {
    int gid = blockIdx.x * 1024 + threadIdx.x;
    if (gid < NN) row_off[gid] += bpref[blockIdx.x];
    if (gid == 0) row_off[NN] = NE;      // total degree is exactly NE
}

__global__ void initcur_k(const int* __restrict__ row_off, int* __restrict__ cursor) {
    int i = blockIdx.x * blockDim.x + threadIdx.x;
    if (i < NN) cursor[i] = row_off[i];
}

// ---------------- scatter + fused per-edge layer-1 attention weights, 4 edges/thread ----------------
#define SCAT_T (NE / 4)   // 200000 threads, edges t, t+200k, t+400k, t+600k
__global__ void scatter_k(const int* __restrict__ src, const int* __restrict__ dst,
                          int* __restrict__ cursor,
                          const float* __restrict__ sI, const float* __restrict__ sJ,
                          int* __restrict__ csr, int* __restrict__ cdst,
                          float4* __restrict__ ep4) {
    int t = blockIdx.x * blockDim.x + threadIdx.x;
    if (t >= SCAT_T) return;
    int e0 = t, e1 = t + SCAT_T, e2 = t + 2 * SCAT_T, e3 = t + 3 * SCAT_T;
    int s0 = src[e0], s1 = src[e1], s2 = src[e2], s3 = src[e3];
    int d0 = dst[e0], d1 = dst[e1], d2 = dst[e2], d3 = dst[e3];
    // cursor pre-initialized to row_off: atomic return IS the position
    int p0 = atomicAdd(&cursor[d0], 1);
    int p1 = atomicAdd(&cursor[d1], 1);
    int p2 = atomicAdd(&cursor[d2], 1);
    int p3 = atomicAdd(&cursor[d3], 1);
    float4 si0 = *(const float4*)&sI[d0 * 4];
    float4 si1 = *(const float4*)&sI[d1 * 4];
    float4 si2 = *(const float4*)&sI[d2 * 4];
    float4 si3 = *(const float4*)&sI[d3 * 4];
    float4 sj0 = *(const float4*)&sJ[s0 * 4];
    float4 sj1 = *(const float4*)&sJ[s1 * 4];
    float4 sj2 = *(const float4*)&sJ[s2 * 4];
    float4 sj3 = *(const float4*)&sJ[s3 * 4];
    float4 r0, r1, r2, r3;
    r0.x = __expf(lrelu(si0.x + sj0.x)); r0.y = __expf(lrelu(si0.y + sj0.y));
    r0.z = __expf(lrelu(si0.z + sj0.z)); r0.w = __expf(lrelu(si0.w + sj0.w));
    r1.x = __expf(lrelu(si1.x + sj1.x)); r1.y = __expf(lrelu(si1.y + sj1.y));
    r1.z = __expf(lrelu(si1.z + sj1.z)); r1.w = __expf(lrelu(si1.w + sj1.w));
    r2.x = __expf(lrelu(si2.x + sj2.x)); r2.y = __expf(lrelu(si2.y + sj2.y));
    r2.z = __expf(lrelu(si2.z + sj2.z)); r2.w = __expf(lrelu(si2.w + sj2.w));
    r3.x = __expf(lrelu(si3.x + sj3.x)); r3.y = __expf(lrelu(si3.y + sj3.y));
    r3.z = __expf(lrelu(si3.z + sj3.z)); r3.w = __expf(lrelu(si3.w + sj3.w));
    csr[p0] = s0; csr[p1] = s1; csr[p2] = s2; csr[p3] = s3;
    cdst[p0] = d0; cdst[p1] = d1; cdst[p2] = d2; cdst[p3] = d3;
    ep4[p0] = r0; ep4[p1] = r1; ep4[p2] = r2; ep4[p3] = r3;
}

// ---------------- layer-1 aggregation: streams precomputed ep, fp16 row gathers ----------------
__global__ __launch_bounds__(256, 6) void agg1_k(const __half* __restrict__ feah,
                                                 const float* __restrict__ sI,
                                                 const float* __restrict__ sJ,
                                                 const float* __restrict__ epf,
                                                 const int* __restrict__ row_off,
                                                 const int* __restrict__ csr,
                                                 const float* __restrict__ bias,
                                                 float* __restrict__ out) {
    int wid = threadIdx.x >> 6, lane = threadIdx.x & 63;
    int n = blockIdx.x * 4 + wid;
    if (n >= NN) return;
    int h = lane >> 4;           // head of this lane's channels
    int c = lane * 4;            // channel group
    // self loop
    float p = __expf(lrelu(sI[n * 4 + h] + sJ[n * 4 + h]));
    float asum = p;
    H4 vs = *(const H4*)&feah[(size_t)n * F1 + c];
    float2 sx = __half22float2(vs.a), sy = __half22float2(vs.b);
    float4 acc = make_float4(sx.x * p, sx.y * p, sy.x * p, sy.y * p);
    int beg = row_off[n], end = row_off[n + 1];
    int e = beg;
    for (; e + 8 <= end; e += 8) {
        int s0 = csr[e + 0], s1 = csr[e + 1], s2 = csr[e + 2], s3 = csr[e + 3];
        int s4 = csr[e + 4], s5 = csr[e + 5], s6 = csr[e + 6], s7 = csr[e + 7];
        float p0 = epf[(e + 0) * 4 + h], p1 = epf[(e + 1) * 4 + h];
        float p2 = epf[(e + 2) * 4 + h], p3 = epf[(e + 3) * 4 + h];
        float p4 = epf[(e + 4) * 4 + h], p5 = epf[(e + 5) * 4 + h];
        float p6 = epf[(e + 6) * 4 + h], p7 = epf[(e + 7) * 4 + h];
        H4 v0 = *(const H4*)&feah[(size_t)s0 * F1 + c];
        H4 v1 = *(const H4*)&feah[(size_t)s1 * F1 + c];
        H4 v2 = *(const H4*)&feah[(size_t)s2 * F1 + c];
        H4 v3 = *(const H4*)&feah[(size_t)s3 * F1 + c];
        H4 v4 = *(const H4*)&feah[(size_t)s4 * F1 + c];
        H4 v5 = *(const H4*)&feah[(size_t)s5 * F1 + c];
        H4 v6 = *(const H4*)&feah[(size_t)s6 * F1 + c];
        H4 v7 = *(const H4*)&feah[(size_t)s7 * F1 + c];
        asum += ((p0 + p1) + (p2 + p3)) + ((p4 + p5) + (p6 + p7));
        float2 x0 = __half22float2(v0.a), y0 = __half22float2(v0.b);
        float2 x1 = __half22float2(v1.a), y1 = __half22float2(v1.b);
        float2 x2 = __half22float2(v2.a), y2 = __half22float2(v2.b);
        float2 x3 = __half22float2(v3.a), y3 = __half22float2(v3.b);
        float2 x4 = __half22float2(v4.a), y4 = __half22float2(v4.b);
        float2 x5 = __half22float2(v5.a), y5 = __half22float2(v5.b);
        float2 x6 = __half22float2(v6.a), y6 = __half22float2(v6.b);
        float2 x7 = __half22float2(v7.a), y7 = __half22float2(v7.b);
        acc.x += (x0.x * p0 + x1.x * p1 + x2.x * p2 + x3.x * p3)
               + (x4.x * p4 + x5.x * p5 + x6.x * p6 + x7.x * p7);
        acc.y += (x0.y * p0 + x1.y * p1 + x2.y * p2 + x3.y * p3)
               + (x4.y * p4 + x5.y * p5 + x6.y * p6 + x7.y * p7);
        acc.z += (y0.x * p0 + y1.x * p1 + y2.x * p2 + y3.x * p3)
               + (y4.x * p4 + y5.x * p5 + y6.x * p6 + y7.x * p7);
        acc.w += (y0.y * p0 + y1.y * p1 + y2.y * p2 + y3.y * p3)
               + (y4.y * p4 + y5.y * p5 + y6.y * p6 + y7.y * p7);
    }
    for (; e + 4 <= end; e += 4) {
        int s0 = csr[e], s1 = csr[e + 1], s2 = csr[e + 2], s3 = csr[e + 3];
        float p0 = epf[(e + 0) * 4 + h], p1 = epf[(e + 1) * 4 + h];
        float p2 = epf[(e + 2) * 4 + h], p3 = epf[(e + 3) * 4 + h];
        H4 v0 = *(const H4*)&feah[(size_t)s0 * F1 + c];
        H4 v1 = *(const H4*)&feah[(size_t)s1 * F1 + c];
        H4 v2 = *(const H4*)&feah[(size_t)s2 * F1 + c];
        H4 v3 = *(const H4*)&feah[(size_t)s3 * F1 + c];
        asum += (p0 + p1) + (p2 + p3);
        float2 x0 = __half22float2(v0.a), y0 = __half22float2(v0.b);
        float2 x1 = __half22float2(v1.a), y1 = __half22float2(v1.b);
        float2 x2 = __half22float2(v2.a), y2 = __half22float2(v2.b);
        float2 x3 = __half22float2(v3.a), y3 = __half22float2(v3.b);
        acc.x += x0.x * p0 + x1.x * p1 + x2.x * p2 + x3.x * p3;
        acc.y += x0.y * p0 + x1.y * p1 + x2.y * p2 + x3.y * p3;
        acc.z += y0.x * p0 + y1.x * p1 + y2.x * p2 + y3.x * p3;
        acc.w += y0.y * p0 + y1.y * p1 + y2.y * p2 + y3.y * p3;
    }
    for (; e < end; ++e) {
        int s = csr[e];
        float pe = epf[e * 4 + h];
        asum += pe;
        H4 v = *(const H4*)&feah[(size_t)s * F1 + c];
        float2 x = __half22float2(v.a), y = __half22float2(v.b);
        acc.x += x.x * pe; acc.y += x.y * pe;
        acc.z += y.x * pe; acc.w += y.y * pe;
    }
    float inv = 1.0f / (asum + 1e-16f);
    float4 bv = *(const float4*)&bias[c];
    float4 o;
    o.x = fmaxf(acc.x * inv + bv.x, 0.f);
    o.y = fmaxf(acc.y * inv + bv.y, 0.f);
    o.z = fmaxf(acc.z * inv + bv.z, 0.f);
    o.w = fmaxf(acc.w * inv + bv.w, 0.f);
    *(float4*)&out[(size_t)n * F1 + c] = o;
}

// ---------------- GEMM2: thread-per-(node, 8 classes), W2 staged once ----------------
#define G2N 51   // nodes per block (255 threads = 51 * 5 groups)
__global__ __launch_bounds__(256) void gemm2_k(const float* __restrict__ h1,
                                               const float* __restrict__ W2,
                                               const float* __restrict__ b2,
                                               const float* __restrict__ att2,
                                               float* __restrict__ fea2,
                                               float* __restrict__ s2I,
                                               float* __restrict__ s2J) {
    __shared__ float Ws[F1 * CLS];         // 40 KB
    __shared__ float redI[G2N][5];
    __shared__ float redJ[G2N][5];
    int tid = threadIdx.x;
    for (int i = tid * 4; i < F1 * CLS; i += 256 * 4)
        *(float4*)&Ws[i] = *(const float4*)&W2[i];
    __syncthreads();
    int nl = tid / 5, g = tid - nl * 5;
    int n = blockIdx.x * G2N + nl;
    bool active = (tid < 255) && (n < NN);
    float acc[8];
    int c0 = g * 8;
    if (active) {
        float4 bb0 = *(const float4*)&b2[c0];
        float4 bb1 = *(const float4*)&b2[c0 + 4];
        acc[0] = bb0.x; acc[1] = bb0.y; acc[2] = bb0.z; acc[3] = bb0.w;
        acc[4] = bb1.x; acc[5] = bb1.y; acc[6] = bb1.z; acc[7] = bb1.w;
        const float* hrow = h1 + (size_t)n * F1;
        for (int k = 0; k < F1; k += 4) {
            float4 h4 = *(const float4*)&hrow[k];
            float hk[4] = {h4.x, h4.y, h4.z, h4.w};
            #pragma unroll
            for (int kk = 0; kk < 4; ++kk) {
                float4 w0 = *(const float4*)&Ws[(k + kk) * CLS + c0];
                float4 w1 = *(const float4*)&Ws[(k + kk) * CLS + c0 + 4];
                acc[0] += hk[kk] * w0.x; acc[1] += hk[kk] * w0.y;
                acc[2] += hk[kk] * w0.z; acc[3] += hk[kk] * w0.w;
                acc[4] += hk[kk] * w1.x; acc[5] += hk[kk] * w1.y;
                acc[6] += hk[kk] * w1.z; acc[7] += hk[kk] * w1.w;
            }
        }
        float sIp = 0.f, sJp = 0.f;
        #pragma unroll
        for (int j = 0; j < 8; ++j) {
            sIp += acc[j] * att2[c0 + j];
            sJp += acc[j] * att2[CLS + c0 + j];
        }
        *(float4*)&fea2[(size_t)n * CLS + c0] = make_float4(acc[0], acc[1], acc[2], acc[3]);
        *(float4*)&fea2[(size_t)n * CLS + c0 + 4] = make_float4(acc[4], acc[5], acc[6], acc[7]);
        redI[nl][g] = sIp;
        redJ[nl][g] = sJp;
    }
    __syncthreads();
    if (active && g == 0) {
        float si = redI[nl][0] + redI[nl][1] + redI[nl][2] + redI[nl][3] + redI[nl][4];
        float sj = redJ[nl][0] + redJ[nl][1] + redJ[nl][2] + redJ[nl][3] + redJ[nl][4];
        s2I[n] = si;
        s2J[n] = sj;
    }
}

// ---------------- per-edge layer-2 attention weights (CSR order) ----------------
__global__ void ep2_k(const int* __restrict__ csr, const int* __restrict__ cdst,
                      const float* __restrict__ s2I, const float* __restrict__ s2J,
                      float* __restrict__ ep2) {
    int e = blockIdx.x * blockDim.x + threadIdx.x;
    if (e >= NE) return;
    ep2[e] = __expf(lrelu(s2I[cdst[e]] + s2J[csr[e]]));
}

// ---------------- layer-2 aggregation + bias + row softmax (streams ep2) ----------------
__global__ __launch_bounds__(256) void agg2_k(const float* __restrict__ fea2,
                                              const float* __restrict__ s2I,
                                              const float* __restrict__ s2J,
                                              const float* __restrict__ ep2,
                                              const int* __restrict__ row_off,
                                              const int* __restrict__ csr,
                                              const float* __restrict__ bias2,
                                              float* __restrict__ out) {
    int wid = threadIdx.x >> 6, lane = threadIdx.x & 63;
    int n = blockIdx.x * 4 + wid;
    if (n >= NN) return;
    float si = s2I[n], sjn = s2J[n];
    int c = lane < CLS ? lane : 0;
    float p = __expf(lrelu(si + sjn));
    float asum = p;
    float acc = fea2[(size_t)n * CLS + c] * p;
    int beg = row_off[n], end = row_off[n + 1];
    int e = beg;
    for (; e + 8 <= end; e += 8) {
        int s0 = csr[e + 0], s1 = csr[e + 1], s2 = csr[e + 2], s3 = csr[e + 3];
        int s4 = csr[e + 4], s5 = csr[e + 5], s6 = csr[e + 6], s7 = csr[e + 7];
        float p0 = ep2[e + 0], p1 = ep2[e + 1], p2 = ep2[e + 2], p3 = ep2[e + 3];
        float p4 = ep2[e + 4], p5 = ep2[e + 5], p6 = ep2[e + 6], p7 = ep2[e + 7];
        float f0 = fea2[(size_t)s0 * CLS + c];
        float f1 = fea2[(size_t)s1 * CLS + c];
        float f2 = fea2[(size_t)s2 * CLS + c];
        float f3 = fea2[(size_t)s3 * CLS + c];
        float f4 = fea2[(size_t)s4 * CLS + c];
        float f5 = fea2[(size_t)s5 * CLS + c];
        float f6 = fea2[(size_t)s6 * CLS + c];
        float f7 = fea2[(size_t)s7 * CLS + c];
        asum += ((p0 + p1) + (p2 + p3)) + ((p4 + p5) + (p6 + p7));
        acc += (f0 * p0 + f1 * p1 + f2 * p2 + f3 * p3)
             + (f4 * p4 + f5 * p5 + f6 * p6 + f7 * p7);
    }
    for (; e < end; ++e) {
        int s = csr[e];
        float pe = ep2[e];
        asum += pe;
        acc += fea2[(size_t)s * CLS + c] * pe;
    }
    float row = acc / (asum + 1e-16f) + bias2[c];
    float v = (lane < CLS) ? row : -3.0e38f;
    float vm = v;
    #pragma unroll
    for (int off = 32; off; off >>= 1) vm = fmaxf(vm, __shfl_xor(vm, off));
    float ex = (lane < CLS) ? __expf(v - vm) : 0.f;
    float es = ex;
    #pragma unroll
    for (int off = 32; off; off >>= 1) es += __shfl_xor(es, off);
    if (lane < CLS) out[(size_t)n * CLS + lane] = ex / es;
}

extern "C" void kernel_launch(void* const* d_in, const int* in_sizes, int n_in,
                              void* d_out, int out_size, void* d_ws, size_t ws_size,
                              hipStream_t stream) {
    const float* x     = (const float*)d_in[0];
    const int*   ei    = (const int*)d_in[1];
    const float* w1    = (const float*)d_in[2];
    const float* b1    = (const float*)d_in[3];
    const float* att1  = (const float*)d_in[4];
    const float* bias1 = (const float*)d_in[5];
    const float* w2    = (const float*)d_in[6];
    const float* b2    = (const float*)d_in[7];
    const float* att2  = (const float*)d_in[8];
    const float* bias2 = (const float*)d_in[9];
    const int* src = ei;
    const int* dst = ei + NE;
    float* out = (float*)d_out;

    char* p = (char*)d_ws;
    auto alloc = [&](size_t bytes) {
        char* r = p;
        p += (bytes + 255) & ~(size_t)255;
        return r;
    };
    __half* fea1h = (__half*)alloc((size_t)NN * F1 * 2);
    float* h1     = (float*)alloc((size_t)NN * F1 * 4);
    float* sI1    = (float*)alloc((size_t)NN * 4 * 4);
    float* sJ1    = (float*)alloc((size_t)NN * 4 * 4);
    float* fea2   = (float*)alloc((size_t)NN * CLS * 4);
    float* s2I    = (float*)alloc((size_t)NN * 4);
    float* s2J    = (float*)alloc((size_t)NN * 4);
    int*   deg    = (int*)alloc((size_t)NN * 4);
    int*   cursor = (int*)alloc((size_t)NN * 4);
    int*   row_off= (int*)alloc((size_t)(NN + 1) * 4);
    int*   bsum   = (int*)alloc((size_t)NB * 4);
    int*   bpref  = (int*)alloc((size_t)NB * 4);
    int*   csr    = (int*)alloc((size_t)NE * 4);
    int*   cdst   = (int*)alloc((size_t)NE * 4);
    float* ep1    = (float*)alloc((size_t)NE * 4 * 4);
    float* ep2    = (float*)alloc((size_t)NE * 4);

    hipMemsetAsync(deg, 0, (size_t)NN * 4, stream);

    dim3 g1((NN + BM - 1) / BM, F1 / BN);
    gemm1_k<<<g1, 256, 0, stream>>>(x, w1, b1, att1, fea1h, sI1, sJ1);
    hist_k<<<(NE + 255) / 256, 256, 0, stream>>>(dst, deg);
    scan1_k<<<NB, 1024, 0, stream>>>(deg, row_off, bsum);
    scan2_k<<<1, 64, 0, stream>>>(bsum, bpref);
    scan3_k<<<NB, 1024, 0, stream>>>(row_off, bpref);
    initcur_k<<<(NN + 255) / 256, 256, 0, stream>>>(row_off, cursor);
    scatter_k<<<(SCAT_T + 255) / 256, 256, 0, stream>>>(src, dst, cursor,
                                                        sI1, sJ1, csr, cdst, (float4*)ep1);
    agg1_k<<<(NN + 3) / 4, 256, 0, stream>>>(fea1h, sI1, sJ1, ep1, row_off, csr, bias1, h1);
    gemm2_k<<<(NN + G2N - 1) / G2N, 256, 0, stream>>>(h1, w2, b2, att2, fea2, s2I, s2J);
    ep2_k<<<(NE + 255) / 256, 256, 0, stream>>>(csr, cdst, s2I, s2J, ep2);
    agg2_k<<<(NN + 3) / 4, 256, 0, stream>>>(fea2, s2I, s2J, ep2, row_off, csr, bias2, out);
}

// Round 8
// 283.007 us; speedup vs baseline: 1.0939x; 1.0939x over previous
//
#include <hip/hip_runtime.h>
#include <hip/hip_fp16.h>

#define NN 50000
#define NE 800000
#define INFEAT 128
#define F1 256
#define HID 64
#define CLS 40
#define NEGS 0.2f
#define NB 49   // ceil(NN / 1024)

__device__ __forceinline__ float lrelu(float x) { return x > 0.0f ? x : NEGS * x; }

struct alignas(8) H4 { __half2 a, b; };

// ---------------- GEMM1: fea1h = fp16(x @ W1 + b1), fused per-node scores ----------------
// 128x64 tile, 8x4 per thread -> 32 FMA per 3 LDS float4 reads per k
#define BM 128
#define BN 64
#define BK 32
__global__ __launch_bounds__(256) void gemm1_k(const float* __restrict__ A,
                                               const float* __restrict__ W,
                                               const float* __restrict__ b,
                                               const float* __restrict__ att1,
                                               __half* __restrict__ feah,
                                               float* __restrict__ sI,
                                               float* __restrict__ sJ) {
    __shared__ float As[BK][BM + 4];
    __shared__ float Bs[BK][BN];
    int tid = threadIdx.x;
    int row0 = blockIdx.x * BM;
    int head = blockIdx.y;          // BN==HID: one head per column block
    int col0 = head * BN;
    int tx = tid & 15, ty = tid >> 4;
    float acc[8][4] = {};
    for (int k0 = 0; k0 < INFEAT; k0 += BK) {
        {
            int r = tid >> 3;            // 0..31
            int c = (tid & 7) * 4;       // 0..28
            #pragma unroll
            for (int rr = r; rr < BM; rr += 32) {
                int grow = row0 + rr;
                float4 v = make_float4(0.f, 0.f, 0.f, 0.f);
                if (grow < NN) v = *(const float4*)&A[(size_t)grow * INFEAT + k0 + c];
                As[c + 0][rr] = v.x; As[c + 1][rr] = v.y;
                As[c + 2][rr] = v.z; As[c + 3][rr] = v.w;
            }
        }
        {
            int r = tid >> 4;            // 0..15
            int c = (tid & 15) * 4;
            #pragma unroll
            for (int rr = r; rr < BK; rr += 16)
                *(float4*)&Bs[rr][c] = *(const float4*)&W[(size_t)(k0 + rr) * F1 + col0 + c];
        }
        __syncthreads();
        #pragma unroll
        for (int k = 0; k < BK; ++k) {
            float4 a0 = *(const float4*)&As[k][ty * 8];
            float4 a1 = *(const float4*)&As[k][ty * 8 + 4];
            float4 bv = *(const float4*)&Bs[k][tx * 4];
            float a[8] = {a0.x, a0.y, a0.z, a0.w, a1.x, a1.y, a1.z, a1.w};
            float bb[4] = {bv.x, bv.y, bv.z, bv.w};
            #pragma unroll
            for (int i = 0; i < 8; ++i)
                #pragma unroll
                for (int j = 0; j < 4; ++j) acc[i][j] += a[i] * bb[j];
        }
        __syncthreads();
    }
    int gcol = col0 + tx * 4;
    float4 bv = *(const float4*)&b[gcol];
    float aI0 = att1[head * 2 * HID + tx * 4 + 0];
    float aI1 = att1[head * 2 * HID + tx * 4 + 1];
    float aI2 = att1[head * 2 * HID + tx * 4 + 2];
    float aI3 = att1[head * 2 * HID + tx * 4 + 3];
    float aJ0 = att1[head * 2 * HID + HID + tx * 4 + 0];
    float aJ1 = att1[head * 2 * HID + HID + tx * 4 + 1];
    float aJ2 = att1[head * 2 * HID + HID + tx * 4 + 2];
    float aJ3 = att1[head * 2 * HID + HID + tx * 4 + 3];
    float sIp[8], sJp[8];
    #pragma unroll
    for (int i = 0; i < 8; ++i) {
        float4 o = make_float4(acc[i][0] + bv.x, acc[i][1] + bv.y,
                               acc[i][2] + bv.z, acc[i][3] + bv.w);
        int grow = row0 + ty * 8 + i;
        if (grow < NN) {
            H4 v;
            v.a = __floats2half2_rn(o.x, o.y);
            v.b = __floats2half2_rn(o.z, o.w);
            *(H4*)&feah[(size_t)grow * F1 + gcol] = v;
        }
        sIp[i] = o.x * aI0 + o.y * aI1 + o.z * aI2 + o.w * aI3;
        sJp[i] = o.x * aJ0 + o.y * aJ1 + o.z * aJ2 + o.w * aJ3;
    }
    #pragma unroll
    for (int off = 1; off < 16; off <<= 1) {
        #pragma unroll
        for (int i = 0; i < 8; ++i) {
            sIp[i] += __shfl_xor(sIp[i], off);
            sJp[i] += __shfl_xor(sJp[i], off);
        }
    }
    if (tx == 0) {
        #pragma unroll
        for (int i = 0; i < 8; ++i) {
            int grow = row0 + ty * 8 + i;
            if (grow < NN) {
                sI[grow * 4 + head] = sIp[i];
                sJ[grow * 4 + head] = sJp[i];
            }
        }
    }
}

// ---------------- CSR build ----------------
__global__ void hist_k(const int* __restrict__ dst, int* __restrict__ deg) {
    int e = blockIdx.x * blockDim.x + threadIdx.x;
    if (e < NE) atomicAdd(&deg[dst[e]], 1);
}

// hierarchical scan: 49 blocks of 1024, then 1-wave scan of block sums, then add-back
__global__ __launch_bounds__(1024) void scan1_k(const int* __restrict__ deg,
                                                int* __restrict__ row_off,
                                                int* __restrict__ bsum) {
    __shared__ int tmp[1024];
    int tid = threadIdx.x;
    int gid = blockIdx.x * 1024 + tid;
    int v = (gid < NN) ? deg[gid] : 0;
    tmp[tid] = v;
    __syncthreads();
    #pragma unroll
    for (int off = 1; off < 1024; off <<= 1) {
        int t = (tid >= off) ? tmp[tid - off] : 0;
        __syncthreads();
        tmp[tid] += t;
        __syncthreads();
    }
    if (gid < NN) row_off[gid] = tmp[tid] - v;   // exclusive
    if (tid == 1023) bsum[blockIdx.x] = tmp[1023];
}

__global__ void scan2_k(const int* __restrict__ bsum, int* __restrict__ bpref) {
    int tid = threadIdx.x;           // 64 threads, one wave
    int orig = (tid < NB) ? bsum[tid] : 0;
    int v = orig;
    #pragma unroll
    for (int off = 1; off < 64; off <<= 1) {
        int t = __shfl_up(v, off);
        if (tid >= off) v += t;
    }
    if (tid < NB) bpref[tid] = v - orig;   // exclusive block prefix
}

__global__ __launch_bounds__(1024) void scan3_k(int* __restrict__ row_off,
                                                const int* __restrict__ bpref) {
    int gid = blockIdx.x * 1024 + threadIdx.x;
    if (gid < NN) row_off[gid] += bpref[blockIdx.x];
    if (gid == 0) row_off[NN] = NE;      // total degree is exactly NE
}

__global__ void initcur_k(const int* __restrict__ row_off, int* __restrict__ cursor) {
    int i = blockIdx.x * blockDim.x + threadIdx.x;
    if (i < NN) cursor[i] = row_off[i];
}

// ---------------- scatter + fused per-edge layer-1 attention weights, 4 edges/thread ----------------
#define SCAT_T (NE / 4)   // 200000 threads, edges t, t+200k, t+400k, t+600k
__global__ void scatter_k(const int* __restrict__ src, const int* __restrict__ dst,
                          int* __restrict__ cursor,
                          const float* __restrict__ sI, const float* __restrict__ sJ,
                          int* __restrict__ csr, float4* __restrict__ ep4) {
    int t = blockIdx.x * blockDim.x + threadIdx.x;
    if (t >= SCAT_T) return;
    int e0 = t, e1 = t + SCAT_T, e2 = t + 2 * SCAT_T, e3 = t + 3 * SCAT_T;
    int s0 = src[e0], s1 = src[e1], s2 = src[e2], s3 = src[e3];
    int d0 = dst[e0], d1 = dst[e1], d2 = dst[e2], d3 = dst[e3];
    // cursor pre-initialized to row_off: atomic return IS the position
    int p0 = atomicAdd(&cursor[d0], 1);
    int p1 = atomicAdd(&cursor[d1], 1);
    int p2 = atomicAdd(&cursor[d2], 1);
    int p3 = atomicAdd(&cursor[d3], 1);
    float4 si0 = *(const float4*)&sI[d0 * 4];
    float4 si1 = *(const float4*)&sI[d1 * 4];
    float4 si2 = *(const float4*)&sI[d2 * 4];
    float4 si3 = *(const float4*)&sI[d3 * 4];
    float4 sj0 = *(const float4*)&sJ[s0 * 4];
    float4 sj1 = *(const float4*)&sJ[s1 * 4];
    float4 sj2 = *(const float4*)&sJ[s2 * 4];
    float4 sj3 = *(const float4*)&sJ[s3 * 4];
    float4 r0, r1, r2, r3;
    r0.x = __expf(lrelu(si0.x + sj0.x)); r0.y = __expf(lrelu(si0.y + sj0.y));
    r0.z = __expf(lrelu(si0.z + sj0.z)); r0.w = __expf(lrelu(si0.w + sj0.w));
    r1.x = __expf(lrelu(si1.x + sj1.x)); r1.y = __expf(lrelu(si1.y + sj1.y));
    r1.z = __expf(lrelu(si1.z + sj1.z)); r1.w = __expf(lrelu(si1.w + sj1.w));
    r2.x = __expf(lrelu(si2.x + sj2.x)); r2.y = __expf(lrelu(si2.y + sj2.y));
    r2.z = __expf(lrelu(si2.z + sj2.z)); r2.w = __expf(lrelu(si2.w + sj2.w));
    r3.x = __expf(lrelu(si3.x + sj3.x)); r3.y = __expf(lrelu(si3.y + sj3.y));
    r3.z = __expf(lrelu(si3.z + sj3.z)); r3.w = __expf(lrelu(si3.w + sj3.w));
    csr[p0] = s0; csr[p1] = s1; csr[p2] = s2; csr[p3] = s3;
    ep4[p0] = r0; ep4[p1] = r1; ep4[p2] = r2; ep4[p3] = r3;
}

// ---------------- layer-1 aggregation: streams precomputed ep, fp16 row gathers ----------------
__global__ __launch_bounds__(256, 6) void agg1_k(const __half* __restrict__ feah,
                                                 const float* __restrict__ sI,
                                                 const float* __restrict__ sJ,
                                                 const float* __restrict__ epf,
                                                 const int* __restrict__ row_off,
                                                 const int* __restrict__ csr,
                                                 const float* __restrict__ bias,
                                                 float* __restrict__ out) {
    int wid = threadIdx.x >> 6, lane = threadIdx.x & 63;
    int n = blockIdx.x * 4 + wid;
    if (n >= NN) return;
    int h = lane >> 4;           // head of this lane's channels
    int c = lane * 4;            // channel group
    // self loop
    float p = __expf(lrelu(sI[n * 4 + h] + sJ[n * 4 + h]));
    float asum = p;
    H4 vs = *(const H4*)&feah[(size_t)n * F1 + c];
    float2 sx = __half22float2(vs.a), sy = __half22float2(vs.b);
    float4 acc = make_float4(sx.x * p, sx.y * p, sy.x * p, sy.y * p);
    int beg = row_off[n], end = row_off[n + 1];
    int e = beg;
    for (; e + 8 <= end; e += 8) {
        int s0 = csr[e + 0], s1 = csr[e + 1], s2 = csr[e + 2], s3 = csr[e + 3];
        int s4 = csr[e + 4], s5 = csr[e + 5], s6 = csr[e + 6], s7 = csr[e + 7];
        float p0 = epf[(e + 0) * 4 + h], p1 = epf[(e + 1) * 4 + h];
        float p2 = epf[(e + 2) * 4 + h], p3 = epf[(e + 3) * 4 + h];
        float p4 = epf[(e + 4) * 4 + h], p5 = epf[(e + 5) * 4 + h];
        float p6 = epf[(e + 6) * 4 + h], p7 = epf[(e + 7) * 4 + h];
        H4 v0 = *(const H4*)&feah[(size_t)s0 * F1 + c];
        H4 v1 = *(const H4*)&feah[(size_t)s1 * F1 + c];
        H4 v2 = *(const H4*)&feah[(size_t)s2 * F1 + c];
        H4 v3 = *(const H4*)&feah[(size_t)s3 * F1 + c];
        H4 v4 = *(const H4*)&feah[(size_t)s4 * F1 + c];
        H4 v5 = *(const H4*)&feah[(size_t)s5 * F1 + c];
        H4 v6 = *(const H4*)&feah[(size_t)s6 * F1 + c];
        H4 v7 = *(const H4*)&feah[(size_t)s7 * F1 + c];
        asum += ((p0 + p1) + (p2 + p3)) + ((p4 + p5) + (p6 + p7));
        float2 x0 = __half22float2(v0.a), y0 = __half22float2(v0.b);
        float2 x1 = __half22float2(v1.a), y1 = __half22float2(v1.b);
        float2 x2 = __half22float2(v2.a), y2 = __half22float2(v2.b);
        float2 x3 = __half22float2(v3.a), y3 = __half22float2(v3.b);
        float2 x4 = __half22float2(v4.a), y4 = __half22float2(v4.b);
        float2 x5 = __half22float2(v5.a), y5 = __half22float2(v5.b);
        float2 x6 = __half22float2(v6.a), y6 = __half22float2(v6.b);
        float2 x7 = __half22float2(v7.a), y7 = __half22float2(v7.b);
        acc.x += (x0.x * p0 + x1.x * p1 + x2.x * p2 + x3.x * p3)
               + (x4.x * p4 + x5.x * p5 + x6.x * p6 + x7.x * p7);
        acc.y += (x0.y * p0 + x1.y * p1 + x2.y * p2 + x3.y * p3)
               + (x4.y * p4 + x5.y * p5 + x6.y * p6 + x7.y * p7);
        acc.z += (y0.x * p0 + y1.x * p1 + y2.x * p2 + y3.x * p3)
               + (y4.x * p4 + y5.x * p5 + y6.x * p6 + y7.x * p7);
        acc.w += (y0.y * p0 + y1.y * p1 + y2.y * p2 + y3.y * p3)
               + (y4.y * p4 + y5.y * p5 + y6.y * p6 + y7.y * p7);
    }
    for (; e + 4 <= end; e += 4) {
        int s0 = csr[e], s1 = csr[e + 1], s2 = csr[e + 2], s3 = csr[e + 3];
        float p0 = epf[(e + 0) * 4 + h], p1 = epf[(e + 1) * 4 + h];
        float p2 = epf[(e + 2) * 4 + h], p3 = epf[(e + 3) * 4 + h];
        H4 v0 = *(const H4*)&feah[(size_t)s0 * F1 + c];
        H4 v1 = *(const H4*)&feah[(size_t)s1 * F1 + c];
        H4 v2 = *(const H4*)&feah[(size_t)s2 * F1 + c];
        H4 v3 = *(const H4*)&feah[(size_t)s3 * F1 + c];
        asum += (p0 + p1) + (p2 + p3);
        float2 x0 = __half22float2(v0.a), y0 = __half22float2(v0.b);
        float2 x1 = __half22float2(v1.a), y1 = __half22float2(v1.b);
        float2 x2 = __half22float2(v2.a), y2 = __half22float2(v2.b);
        float2 x3 = __half22float2(v3.a), y3 = __half22float2(v3.b);
        acc.x += x0.x * p0 + x1.x * p1 + x2.x * p2 + x3.x * p3;
        acc.y += x0.y * p0 + x1.y * p1 + x2.y * p2 + x3.y * p3;
        acc.z += y0.x * p0 + y1.x * p1 + y2.x * p2 + y3.x * p3;
        acc.w += y0.y * p0 + y1.y * p1 + y2.y * p2 + y3.y * p3;
    }
    for (; e < end; ++e) {
        int s = csr[e];
        float pe = epf[e * 4 + h];
        asum += pe;
        H4 v = *(const H4*)&feah[(size_t)s * F1 + c];
        float2 x = __half22float2(v.a), y = __half22float2(v.b);
        acc.x += x.x * pe; acc.y += x.y * pe;
        acc.z += y.x * pe; acc.w += y.y * pe;
    }
    float inv = 1.0f / (asum + 1e-16f);
    float4 bv = *(const float4*)&bias[c];
    float4 o;
    o.x = fmaxf(acc.x * inv + bv.x, 0.f);
    o.y = fmaxf(acc.y * inv + bv.y, 0.f);
    o.z = fmaxf(acc.z * inv + bv.z, 0.f);
    o.w = fmaxf(acc.w * inv + bv.w, 0.f);
    *(float4*)&out[(size_t)n * F1 + c] = o;
}

// ---------------- GEMM2: thread-per-(2 nodes, 8 classes), W2 staged once ----------------
#define G2N 102   // nodes per block: 51 pairs, 255 active threads
__global__ __launch_bounds__(256) void gemm2_k(const float* __restrict__ h1,
                                               const float* __restrict__ W2,
                                               const float* __restrict__ b2,
                                               const float* __restrict__ att2,
                                               float* __restrict__ fea2,
                                               float* __restrict__ s2I,
                                               float* __restrict__ s2J) {
    __shared__ float Ws[F1 * CLS];         // 40 KB
    __shared__ float redI[G2N][5];
    __shared__ float redJ[G2N][5];
    int tid = threadIdx.x;
    for (int i = tid * 4; i < F1 * CLS; i += 256 * 4)
        *(float4*)&Ws[i] = *(const float4*)&W2[i];
    __syncthreads();
    int nl = tid / 5, g = tid - nl * 5;    // nl 0..50, g 0..4
    int na = blockIdx.x * G2N + nl * 2;
    int nb = na + 1;
    bool actA = (tid < 255) && (na < NN);
    bool actB = (tid < 255) && (nb < NN);
    int c0 = g * 8;
    float accA[8] = {}, accB[8] = {};
    if (actA) {
        const float* rowA = h1 + (size_t)na * F1;
        const float* rowB = h1 + (size_t)(actB ? nb : na) * F1;
        for (int k = 0; k < F1; k += 4) {
            float4 ha = *(const float4*)&rowA[k];
            float4 hb = *(const float4*)&rowB[k];
            float a[4] = {ha.x, ha.y, ha.z, ha.w};
            float bl[4] = {hb.x, hb.y, hb.z, hb.w};
            #pragma unroll
            for (int kk = 0; kk < 4; ++kk) {
                float4 w0 = *(const float4*)&Ws[(k + kk) * CLS + c0];
                float4 w1 = *(const float4*)&Ws[(k + kk) * CLS + c0 + 4];
                accA[0] += a[kk] * w0.x; accA[1] += a[kk] * w0.y;
                accA[2] += a[kk] * w0.z; accA[3] += a[kk] * w0.w;
                accA[4] += a[kk] * w1.x; accA[5] += a[kk] * w1.y;
                accA[6] += a[kk] * w1.z; accA[7] += a[kk] * w1.w;
                accB[0] += bl[kk] * w0.x; accB[1] += bl[kk] * w0.y;
                accB[2] += bl[kk] * w0.z; accB[3] += bl[kk] * w0.w;
                accB[4] += bl[kk] * w1.x; accB[5] += bl[kk] * w1.y;
                accB[6] += bl[kk] * w1.z; accB[7] += bl[kk] * w1.w;
            }
        }
        float4 bb0 = *(const float4*)&b2[c0];
        float4 bb1 = *(const float4*)&b2[c0 + 4];
        float bias8[8] = {bb0.x, bb0.y, bb0.z, bb0.w, bb1.x, bb1.y, bb1.z, bb1.w};
        float sIa = 0.f, sJa = 0.f, sIb = 0.f, sJb = 0.f;
        #pragma unroll
        for (int j = 0; j < 8; ++j) {
            accA[j] += bias8[j];
            accB[j] += bias8[j];
            float aI = att2[c0 + j], aJ = att2[CLS + c0 + j];
            sIa += accA[j] * aI; sJa += accA[j] * aJ;
            sIb += accB[j] * aI; sJb += accB[j] * aJ;
        }
        *(float4*)&fea2[(size_t)na * CLS + c0]     = make_float4(accA[0], accA[1], accA[2], accA[3]);
        *(float4*)&fea2[(size_t)na * CLS + c0 + 4] = make_float4(accA[4], accA[5], accA[6], accA[7]);
        redI[nl * 2][g] = sIa;
        redJ[nl * 2][g] = sJa;
        if (actB) {
            *(float4*)&fea2[(size_t)nb * CLS + c0]     = make_float4(accB[0], accB[1], accB[2], accB[3]);
            *(float4*)&fea2[(size_t)nb * CLS + c0 + 4] = make_float4(accB[4], accB[5], accB[6], accB[7]);
            redI[nl * 2 + 1][g] = sIb;
            redJ[nl * 2 + 1][g] = sJb;
        }
    }
    __syncthreads();
    if (actA && g == 0) {
        int r = nl * 2;
        s2I[na] = redI[r][0] + redI[r][1] + redI[r][2] + redI[r][3] + redI[r][4];
        s2J[na] = redJ[r][0] + redJ[r][1] + redJ[r][2] + redJ[r][3] + redJ[r][4];
        if (actB) {
            s2I[nb] = redI[r + 1][0] + redI[r + 1][1] + redI[r + 1][2] + redI[r + 1][3] + redI[r + 1][4];
            s2J[nb] = redJ[r + 1][0] + redJ[r + 1][1] + redJ[r + 1][2] + redJ[r + 1][3] + redJ[r + 1][4];
        }
    }
}

// ---------------- layer-2 aggregation + bias + row softmax (one pass, 8-deep) ----------------
__global__ __launch_bounds__(256) void agg2_k(const float* __restrict__ fea2,
                                              const float* __restrict__ s2I,
                                              const float* __restrict__ s2J,
                                              const int* __restrict__ row_off,
                                              const int* __restrict__ csr,
                                              const float* __restrict__ bias2,
                                              float* __restrict__ out) {
    int wid = threadIdx.x >> 6, lane = threadIdx.x & 63;
    int n = blockIdx.x * 4 + wid;
    if (n >= NN) return;
    float si = s2I[n], sjn = s2J[n];
    int c = lane < CLS ? lane : 0;
    float p = __expf(lrelu(si + sjn));
    float asum = p;
    float acc = fea2[(size_t)n * CLS + c] * p;
    int beg = row_off[n], end = row_off[n + 1];
    int e = beg;
    for (; e + 8 <= end; e += 8) {
        int s0 = csr[e + 0], s1 = csr[e + 1], s2 = csr[e + 2], s3 = csr[e + 3];
        int s4 = csr[e + 4], s5 = csr[e + 5], s6 = csr[e + 6], s7 = csr[e + 7];
        float a0 = s2J[s0], a1 = s2J[s1], a2 = s2J[s2], a3 = s2J[s3];
        float a4 = s2J[s4], a5 = s2J[s5], a6 = s2J[s6], a7 = s2J[s7];
        float f0 = fea2[(size_t)s0 * CLS + c];
        float f1 = fea2[(size_t)s1 * CLS + c];
        float f2 = fea2[(size_t)s2 * CLS + c];
        float f3 = fea2[(size_t)s3 * CLS + c];
        float f4 = fea2[(size_t)s4 * CLS + c];
        float f5 = fea2[(size_t)s5 * CLS + c];
        float f6 = fea2[(size_t)s6 * CLS + c];
        float f7 = fea2[(size_t)s7 * CLS + c];
        float p0 = __expf(lrelu(si + a0));
        float p1 = __expf(lrelu(si + a1));
        float p2 = __expf(lrelu(si + a2));
        float p3 = __expf(lrelu(si + a3));
        float p4 = __expf(lrelu(si + a4));
        float p5 = __expf(lrelu(si + a5));
        float p6 = __expf(lrelu(si + a6));
        float p7 = __expf(lrelu(si + a7));
        asum += ((p0 + p1) + (p2 + p3)) + ((p4 + p5) + (p6 + p7));
        acc += (f0 * p0 + f1 * p1 + f2 * p2 + f3 * p3)
             + (f4 * p4 + f5 * p5 + f6 * p6 + f7 * p7);
    }
    for (; e + 4 <= end; e += 4) {
        int s0 = csr[e], s1 = csr[e + 1], s2 = csr[e + 2], s3 = csr[e + 3];
        float p0 = __expf(lrelu(si + s2J[s0]));
        float p1 = __expf(lrelu(si + s2J[s1]));
        float p2 = __expf(lrelu(si + s2J[s2]));
        float p3 = __expf(lrelu(si + s2J[s3]));
        float f0 = fea2[(size_t)s0 * CLS + c];
        float f1 = fea2[(size_t)s1 * CLS + c];
        float f2 = fea2[(size_t)s2 * CLS + c];
        float f3 = fea2[(size_t)s3 * CLS + c];
        asum += (p0 + p1) + (p2 + p3);
        acc += f0 * p0 + f1 * p1 + f2 * p2 + f3 * p3;
    }
    for (; e < end; ++e) {
        int s = csr[e];
        float pe = __expf(lrelu(si + s2J[s]));
        asum += pe;
        acc += fea2[(size_t)s * CLS + c] * pe;
    }
    float row = acc / (asum + 1e-16f) + bias2[c];
    float v = (lane < CLS) ? row : -3.0e38f;
    float vm = v;
    #pragma unroll
    for (int off = 32; off; off >>= 1) vm = fmaxf(vm, __shfl_xor(vm, off));
    float ex = (lane < CLS) ? __expf(v - vm) : 0.f;
    float es = ex;
    #pragma unroll
    for (int off = 32; off; off >>= 1) es += __shfl_xor(es, off);
    if (lane < CLS) out[(size_t)n * CLS + lane] = ex / es;
}

extern "C" void kernel_launch(void* const* d_in, const int* in_sizes, int n_in,
                              void* d_out, int out_size, void* d_ws, size_t ws_size,
                              hipStream_t stream) {
    const float* x     = (const float*)d_in[0];
    const int*   ei    = (const int*)d_in[1];
    const float* w1    = (const float*)d_in[2];
    const float* b1    = (const float*)d_in[3];
    const float* att1  = (const float*)d_in[4];
    const float* bias1 = (const float*)d_in[5];
    const float* w2    = (const float*)d_in[6];
    const float* b2    = (const float*)d_in[7];
    const float* att2  = (const float*)d_in[8];
    const float* bias2 = (const float*)d_in[9];
    const int* src = ei;
    const int* dst = ei + NE;
    float* out = (float*)d_out;

    char* p = (char*)d_ws;
    auto alloc = [&](size_t bytes) {
        char* r = p;
        p += (bytes + 255) & ~(size_t)255;
        return r;
    };
    __half* fea1h = (__half*)alloc((size_t)NN * F1 * 2);
    float* h1     = (float*)alloc((size_t)NN * F1 * 4);
    float* sI1    = (float*)alloc((size_t)NN * 4 * 4);
    float* sJ1    = (float*)alloc((size_t)NN * 4 * 4);
    float* fea2   = (float*)alloc((size_t)NN * CLS * 4);
    float* s2I    = (float*)alloc((size_t)NN * 4);
    float* s2J    = (float*)alloc((size_t)NN * 4);
    int*   deg    = (int*)alloc((size_t)NN * 4);
    int*   cursor = (int*)alloc((size_t)NN * 4);
    int*   row_off= (int*)alloc((size_t)(NN + 1) * 4);
    int*   bsum   = (int*)alloc((size_t)NB * 4);
    int*   bpref  = (int*)alloc((size_t)NB * 4);
    int*   csr    = (int*)alloc((size_t)NE * 4);
    float* ep1    = (float*)alloc((size_t)NE * 4 * 4);

    hipMemsetAsync(deg, 0, (size_t)NN * 4, stream);

    dim3 g1((NN + BM - 1) / BM, F1 / BN);
    gemm1_k<<<g1, 256, 0, stream>>>(x, w1, b1, att1, fea1h, sI1, sJ1);
    hist_k<<<(NE + 255) / 256, 256, 0, stream>>>(dst, deg);
    scan1_k<<<NB, 1024, 0, stream>>>(deg, row_off, bsum);
    scan2_k<<<1, 64, 0, stream>>>(bsum, bpref);
    scan3_k<<<NB, 1024, 0, stream>>>(row_off, bpref);
    initcur_k<<<(NN + 255) / 256, 256, 0, stream>>>(row_off, cursor);
    scatter_k<<<(SCAT_T + 255) / 256, 256, 0, stream>>>(src, dst, cursor,
                                                        sI1, sJ1, csr, (float4*)ep1);
    agg1_k<<<(NN + 3) / 4, 256, 0, stream>>>(fea1h, sI1, sJ1, ep1, row_off, csr, bias1, h1);
    gemm2_k<<<(NN + G2N - 1) / G2N, 256, 0, stream>>>(h1, w2, b2, att2, fea2, s2I, s2J);
    agg2_k<<<(NN + 3) / 4, 256, 0, stream>>>(fea2, s2I, s2J, row_off, csr, bias2, out);
}

// Round 9
// 258.348 us; speedup vs baseline: 1.1983x; 1.0955x over previous
//
#include <hip/hip_runtime.h>
#include <hip/hip_fp16.h>

#define NN 50000
#define NE 800000
#define INFEAT 128
#define F1 256
#define HID 64
#define CLS 40
#define NEGS 0.2f
#define NB 49   // ceil(NN / 1024)

__device__ __forceinline__ float lrelu(float x) { return x > 0.0f ? x : NEGS * x; }

struct alignas(8) H4 { __half2 a, b; };

// ---------------- GEMM1: fea1h = fp16(x @ W1 + b1), fused per-node scores ----------------
// 128x64 tile, 8x4 per thread -> 32 FMA per 3 LDS float4 reads per k
#define BM 128
#define BN 64
#define BK 32
__global__ __launch_bounds__(256) void gemm1_k(const float* __restrict__ A,
                                               const float* __restrict__ W,
                                               const float* __restrict__ b,
                                               const float* __restrict__ att1,
                                               __half* __restrict__ feah,
                                               float* __restrict__ sI,
                                               float* __restrict__ sJ) {
    __shared__ float As[BK][BM + 4];
    __shared__ float Bs[BK][BN];
    int tid = threadIdx.x;
    int row0 = blockIdx.x * BM;
    int head = blockIdx.y;          // BN==HID: one head per column block
    int col0 = head * BN;
    int tx = tid & 15, ty = tid >> 4;
    float acc[8][4] = {};
    for (int k0 = 0; k0 < INFEAT; k0 += BK) {
        {
            int r = tid >> 3;            // 0..31
            int c = (tid & 7) * 4;       // 0..28
            #pragma unroll
            for (int rr = r; rr < BM; rr += 32) {
                int grow = row0 + rr;
                float4 v = make_float4(0.f, 0.f, 0.f, 0.f);
                if (grow < NN) v = *(const float4*)&A[(size_t)grow * INFEAT + k0 + c];
                As[c + 0][rr] = v.x; As[c + 1][rr] = v.y;
                As[c + 2][rr] = v.z; As[c + 3][rr] = v.w;
            }
        }
        {
            int r = tid >> 4;            // 0..15
            int c = (tid & 15) * 4;
            #pragma unroll
            for (int rr = r; rr < BK; rr += 16)
                *(float4*)&Bs[rr][c] = *(const float4*)&W[(size_t)(k0 + rr) * F1 + col0 + c];
        }
        __syncthreads();
        #pragma unroll
        for (int k = 0; k < BK; ++k) {
            float4 a0 = *(const float4*)&As[k][ty * 8];
            float4 a1 = *(const float4*)&As[k][ty * 8 + 4];
            float4 bv = *(const float4*)&Bs[k][tx * 4];
            float a[8] = {a0.x, a0.y, a0.z, a0.w, a1.x, a1.y, a1.z, a1.w};
            float bb[4] = {bv.x, bv.y, bv.z, bv.w};
            #pragma unroll
            for (int i = 0; i < 8; ++i)
                #pragma unroll
                for (int j = 0; j < 4; ++j) acc[i][j] += a[i] * bb[j];
        }
        __syncthreads();
    }
    int gcol = col0 + tx * 4;
    float4 bv = *(const float4*)&b[gcol];
    float aI0 = att1[head * 2 * HID + tx * 4 + 0];
    float aI1 = att1[head * 2 * HID + tx * 4 + 1];
    float aI2 = att1[head * 2 * HID + tx * 4 + 2];
    float aI3 = att1[head * 2 * HID + tx * 4 + 3];
    float aJ0 = att1[head * 2 * HID + HID + tx * 4 + 0];
    float aJ1 = att1[head * 2 * HID + HID + tx * 4 + 1];
    float aJ2 = att1[head * 2 * HID + HID + tx * 4 + 2];
    float aJ3 = att1[head * 2 * HID + HID + tx * 4 + 3];
    float sIp[8], sJp[8];
    #pragma unroll
    for (int i = 0; i < 8; ++i) {
        float4 o = make_float4(acc[i][0] + bv.x, acc[i][1] + bv.y,
                               acc[i][2] + bv.z, acc[i][3] + bv.w);
        int grow = row0 + ty * 8 + i;
        if (grow < NN) {
            H4 v;
            v.a = __floats2half2_rn(o.x, o.y);
            v.b = __floats2half2_rn(o.z, o.w);
            *(H4*)&feah[(size_t)grow * F1 + gcol] = v;
        }
        sIp[i] = o.x * aI0 + o.y * aI1 + o.z * aI2 + o.w * aI3;
        sJp[i] = o.x * aJ0 + o.y * aJ1 + o.z * aJ2 + o.w * aJ3;
    }
    #pragma unroll
    for (int off = 1; off < 16; off <<= 1) {
        #pragma unroll
        for (int i = 0; i < 8; ++i) {
            sIp[i] += __shfl_xor(sIp[i], off);
            sJp[i] += __shfl_xor(sJp[i], off);
        }
    }
    if (tx == 0) {
        #pragma unroll
        for (int i = 0; i < 8; ++i) {
            int grow = row0 + ty * 8 + i;
            if (grow < NN) {
                sI[grow * 4 + head] = sIp[i];
                sJ[grow * 4 + head] = sJp[i];
            }
        }
    }
}

// ---------------- CSR build: histogram harvests the ordinal ----------------
__global__ void hist_k(const int* __restrict__ dst, int* __restrict__ deg,
                       int* __restrict__ ord) {
    int e = blockIdx.x * blockDim.x + threadIdx.x;
    if (e < NE) ord[e] = atomicAdd(&deg[dst[e]], 1);
}

// hierarchical scan: 49 blocks of 1024, then 1-wave scan of block sums, then add-back
__global__ __launch_bounds__(1024) void scan1_k(const int* __restrict__ deg,
                                                int* __restrict__ row_off,
                                                int* __restrict__ bsum) {
    __shared__ int tmp[1024];
    int tid = threadIdx.x;
    int gid = blockIdx.x * 1024 + tid;
    int v = (gid < NN) ? deg[gid] : 0;
    tmp[tid] = v;
    __syncthreads();
    #pragma unroll
    for (int off = 1; off < 1024; off <<= 1) {
        int t = (tid >= off) ? tmp[tid - off] : 0;
        __syncthreads();
        tmp[tid] += t;
        __syncthreads();
    }
    if (gid < NN) row_off[gid] = tmp[tid] - v;   // exclusive
    if (tid == 1023) bsum[blockIdx.x] = tmp[1023];
}

__global__ void scan2_k(const int* __restrict__ bsum, int* __restrict__ bpref) {
    int tid = threadIdx.x;           // 64 threads, one wave
    int orig = (tid < NB) ? bsum[tid] : 0;
    int v = orig;
    #pragma unroll
    for (int off = 1; off < 64; off <<= 1) {
        int t = __shfl_up(v, off);
        if (tid >= off) v += t;
    }
    if (tid < NB) bpref[tid] = v - orig;   // exclusive block prefix
}

__global__ __launch_bounds__(1024) void scan3_k(int* __restrict__ row_off,
                                                const int* __restrict__ bpref) {
    int gid = blockIdx.x * 1024 + threadIdx.x;
    if (gid < NN) row_off[gid] += bpref[blockIdx.x];
    if (gid == 0) row_off[NN] = NE;      // total degree is exactly NE
}

// ---------------- scatter: atomic-free (pos = row_off[dst] + ord), fused ep1 ----------------
__global__ void scatter_k(const int* __restrict__ src, const int* __restrict__ dst,
                          const int* __restrict__ ord, const int* __restrict__ row_off,
                          const float* __restrict__ sI, const float* __restrict__ sJ,
                          int* __restrict__ csr, float4* __restrict__ ep4) {
    int e = blockIdx.x * blockDim.x + threadIdx.x;
    if (e >= NE) return;
    int s = src[e], d = dst[e];
    int pos = row_off[d] + ord[e];
    float4 si = *(const float4*)&sI[d * 4];
    float4 sj = *(const float4*)&sJ[s * 4];
    float4 r;
    r.x = __expf(lrelu(si.x + sj.x));
    r.y = __expf(lrelu(si.y + sj.y));
    r.z = __expf(lrelu(si.z + sj.z));
    r.w = __expf(lrelu(si.w + sj.w));
    csr[pos] = s;
    ep4[pos] = r;
}

// ---------------- layer-1 aggregation: streams precomputed ep, fp16 row gathers ----------------
__global__ __launch_bounds__(256, 6) void agg1_k(const __half* __restrict__ feah,
                                                 const float* __restrict__ sI,
                                                 const float* __restrict__ sJ,
                                                 const float* __restrict__ epf,
                                                 const int* __restrict__ row_off,
                                                 const int* __restrict__ csr,
                                                 const float* __restrict__ bias,
                                                 float* __restrict__ out) {
    int wid = threadIdx.x >> 6, lane = threadIdx.x & 63;
    int n = blockIdx.x * 4 + wid;
    if (n >= NN) return;
    int h = lane >> 4;           // head of this lane's channels
    int c = lane * 4;            // channel group
    // self loop
    float p = __expf(lrelu(sI[n * 4 + h] + sJ[n * 4 + h]));
    float asum = p;
    H4 vs = *(const H4*)&feah[(size_t)n * F1 + c];
    float2 sx = __half22float2(vs.a), sy = __half22float2(vs.b);
    float4 acc = make_float4(sx.x * p, sx.y * p, sy.x * p, sy.y * p);
    int beg = row_off[n], end = row_off[n + 1];
    int e = beg;
    for (; e + 8 <= end; e += 8) {
        int s0 = csr[e + 0], s1 = csr[e + 1], s2 = csr[e + 2], s3 = csr[e + 3];
        int s4 = csr[e + 4], s5 = csr[e + 5], s6 = csr[e + 6], s7 = csr[e + 7];
        float p0 = epf[(e + 0) * 4 + h], p1 = epf[(e + 1) * 4 + h];
        float p2 = epf[(e + 2) * 4 + h], p3 = epf[(e + 3) * 4 + h];
        float p4 = epf[(e + 4) * 4 + h], p5 = epf[(e + 5) * 4 + h];
        float p6 = epf[(e + 6) * 4 + h], p7 = epf[(e + 7) * 4 + h];
        H4 v0 = *(const H4*)&feah[(size_t)s0 * F1 + c];
        H4 v1 = *(const H4*)&feah[(size_t)s1 * F1 + c];
        H4 v2 = *(const H4*)&feah[(size_t)s2 * F1 + c];
        H4 v3 = *(const H4*)&feah[(size_t)s3 * F1 + c];
        H4 v4 = *(const H4*)&feah[(size_t)s4 * F1 + c];
        H4 v5 = *(const H4*)&feah[(size_t)s5 * F1 + c];
        H4 v6 = *(const H4*)&feah[(size_t)s6 * F1 + c];
        H4 v7 = *(const H4*)&feah[(size_t)s7 * F1 + c];
        asum += ((p0 + p1) + (p2 + p3)) + ((p4 + p5) + (p6 + p7));
        float2 x0 = __half22float2(v0.a), y0 = __half22float2(v0.b);
        float2 x1 = __half22float2(v1.a), y1 = __half22float2(v1.b);
        float2 x2 = __half22float2(v2.a), y2 = __half22float2(v2.b);
        float2 x3 = __half22float2(v3.a), y3 = __half22float2(v3.b);
        float2 x4 = __half22float2(v4.a), y4 = __half22float2(v4.b);
        float2 x5 = __half22float2(v5.a), y5 = __half22float2(v5.b);
        float2 x6 = __half22float2(v6.a), y6 = __half22float2(v6.b);
        float2 x7 = __half22float2(v7.a), y7 = __half22float2(v7.b);
        acc.x += (x0.x * p0 + x1.x * p1 + x2.x * p2 + x3.x * p3)
               + (x4.x * p4 + x5.x * p5 + x6.x * p6 + x7.x * p7);
        acc.y += (x0.y * p0 + x1.y * p1 + x2.y * p2 + x3.y * p3)
               + (x4.y * p4 + x5.y * p5 + x6.y * p6 + x7.y * p7);
        acc.z += (y0.x * p0 + y1.x * p1 + y2.x * p2 + y3.x * p3)
               + (y4.x * p4 + y5.x * p5 + y6.x * p6 + y7.x * p7);
        acc.w += (y0.y * p0 + y1.y * p1 + y2.y * p2 + y3.y * p3)
               + (y4.y * p4 + y5.y * p5 + y6.y * p6 + y7.y * p7);
    }
    for (; e + 4 <= end; e += 4) {
        int s0 = csr[e], s1 = csr[e + 1], s2 = csr[e + 2], s3 = csr[e + 3];
        float p0 = epf[(e + 0) * 4 + h], p1 = epf[(e + 1) * 4 + h];
        float p2 = epf[(e + 2) * 4 + h], p3 = epf[(e + 3) * 4 + h];
        H4 v0 = *(const H4*)&feah[(size_t)s0 * F1 + c];
        H4 v1 = *(const H4*)&feah[(size_t)s1 * F1 + c];
        H4 v2 = *(const H4*)&feah[(size_t)s2 * F1 + c];
        H4 v3 = *(const H4*)&feah[(size_t)s3 * F1 + c];
        asum += (p0 + p1) + (p2 + p3);
        float2 x0 = __half22float2(v0.a), y0 = __half22float2(v0.b);
        float2 x1 = __half22float2(v1.a), y1 = __half22float2(v1.b);
        float2 x2 = __half22float2(v2.a), y2 = __half22float2(v2.b);
        float2 x3 = __half22float2(v3.a), y3 = __half22float2(v3.b);
        acc.x += x0.x * p0 + x1.x * p1 + x2.x * p2 + x3.x * p3;
        acc.y += x0.y * p0 + x1.y * p1 + x2.y * p2 + x3.y * p3;
        acc.z += y0.x * p0 + y1.x * p1 + y2.x * p2 + y3.x * p3;
        acc.w += y0.y * p0 + y1.y * p1 + y2.y * p2 + y3.y * p3;
    }
    for (; e < end; ++e) {
        int s = csr[e];
        float pe = epf[e * 4 + h];
        asum += pe;
        H4 v = *(const H4*)&feah[(size_t)s * F1 + c];
        float2 x = __half22float2(v.a), y = __half22float2(v.b);
        acc.x += x.x * pe; acc.y += x.y * pe;
        acc.z += y.x * pe; acc.w += y.y * pe;
    }
    float inv = 1.0f / (asum + 1e-16f);
    float4 bv = *(const float4*)&bias[c];
    float4 o;
    o.x = fmaxf(acc.x * inv + bv.x, 0.f);
    o.y = fmaxf(acc.y * inv + bv.y, 0.f);
    o.z = fmaxf(acc.z * inv + bv.z, 0.f);
    o.w = fmaxf(acc.w * inv + bv.w, 0.f);
    *(float4*)&out[(size_t)n * F1 + c] = o;
}

// ---------------- GEMM2: thread-per-(2 nodes, 8 classes), W2 staged once ----------------
#define G2N 102   // nodes per block: 51 pairs, 255 active threads
__global__ __launch_bounds__(256) void gemm2_k(const float* __restrict__ h1,
                                               const float* __restrict__ W2,
                                               const float* __restrict__ b2,
                                               const float* __restrict__ att2,
                                               float* __restrict__ fea2,
                                               float* __restrict__ s2I,
                                               float* __restrict__ s2J) {
    __shared__ float Ws[F1 * CLS];         // 40 KB
    __shared__ float redI[G2N][5];
    __shared__ float redJ[G2N][5];
    int tid = threadIdx.x;
    for (int i = tid * 4; i < F1 * CLS; i += 256 * 4)
        *(float4*)&Ws[i] = *(const float4*)&W2[i];
    __syncthreads();
    int nl = tid / 5, g = tid - nl * 5;    // nl 0..50, g 0..4
    int na = blockIdx.x * G2N + nl * 2;
    int nb = na + 1;
    bool actA = (tid < 255) && (na < NN);
    bool actB = (tid < 255) && (nb < NN);
    int c0 = g * 8;
    float accA[8] = {}, accB[8] = {};
    if (actA) {
        const float* rowA = h1 + (size_t)na * F1;
        const float* rowB = h1 + (size_t)(actB ? nb : na) * F1;
        for (int k = 0; k < F1; k += 4) {
            float4 ha = *(const float4*)&rowA[k];
            float4 hb = *(const float4*)&rowB[k];
            float a[4] = {ha.x, ha.y, ha.z, ha.w};
            float bl[4] = {hb.x, hb.y, hb.z, hb.w};
            #pragma unroll
            for (int kk = 0; kk < 4; ++kk) {
                float4 w0 = *(const float4*)&Ws[(k + kk) * CLS + c0];
                float4 w1 = *(const float4*)&Ws[(k + kk) * CLS + c0 + 4];
                accA[0] += a[kk] * w0.x; accA[1] += a[kk] * w0.y;
                accA[2] += a[kk] * w0.z; accA[3] += a[kk] * w0.w;
                accA[4] += a[kk] * w1.x; accA[5] += a[kk] * w1.y;
                accA[6] += a[kk] * w1.z; accA[7] += a[kk] * w1.w;
                accB[0] += bl[kk] * w0.x; accB[1] += bl[kk] * w0.y;
                accB[2] += bl[kk] * w0.z; accB[3] += bl[kk] * w0.w;
                accB[4] += bl[kk] * w1.x; accB[5] += bl[kk] * w1.y;
                accB[6] += bl[kk] * w1.z; accB[7] += bl[kk] * w1.w;
            }
        }
        float4 bb0 = *(const float4*)&b2[c0];
        float4 bb1 = *(const float4*)&b2[c0 + 4];
        float bias8[8] = {bb0.x, bb0.y, bb0.z, bb0.w, bb1.x, bb1.y, bb1.z, bb1.w};
        float sIa = 0.f, sJa = 0.f, sIb = 0.f, sJb = 0.f;
        #pragma unroll
        for (int j = 0; j < 8; ++j) {
            accA[j] += bias8[j];
            accB[j] += bias8[j];
            float aI = att2[c0 + j], aJ = att2[CLS + c0 + j];
            sIa += accA[j] * aI; sJa += accA[j] * aJ;
            sIb += accB[j] * aI; sJb += accB[j] * aJ;
        }
        *(float4*)&fea2[(size_t)na * CLS + c0]     = make_float4(accA[0], accA[1], accA[2], accA[3]);
        *(float4*)&fea2[(size_t)na * CLS + c0 + 4] = make_float4(accA[4], accA[5], accA[6], accA[7]);
        redI[nl * 2][g] = sIa;
        redJ[nl * 2][g] = sJa;
        if (actB) {
            *(float4*)&fea2[(size_t)nb * CLS + c0]     = make_float4(accB[0], accB[1], accB[2], accB[3]);
            *(float4*)&fea2[(size_t)nb * CLS + c0 + 4] = make_float4(accB[4], accB[5], accB[6], accB[7]);
            redI[nl * 2 + 1][g] = sIb;
            redJ[nl * 2 + 1][g] = sJb;
        }
    }
    __syncthreads();
    if (actA && g == 0) {
        int r = nl * 2;
        s2I[na] = redI[r][0] + redI[r][1] + redI[r][2] + redI[r][3] + redI[r][4];
        s2J[na] = redJ[r][0] + redJ[r][1] + redJ[r][2] + redJ[r][3] + redJ[r][4];
        if (actB) {
            s2I[nb] = redI[r + 1][0] + redI[r + 1][1] + redI[r + 1][2] + redI[r + 1][3] + redI[r + 1][4];
            s2J[nb] = redJ[r + 1][0] + redJ[r + 1][1] + redJ[r + 1][2] + redJ[r + 1][3] + redJ[r + 1][4];
        }
    }
}

// ---------------- layer-2 aggregation + bias + row softmax (one pass, 8-deep) ----------------
__global__ __launch_bounds__(256) void agg2_k(const float* __restrict__ fea2,
                                              const float* __restrict__ s2I,
                                              const float* __restrict__ s2J,
                                              const int* __restrict__ row_off,
                                              const int* __restrict__ csr,
                                              const float* __restrict__ bias2,
                                              float* __restrict__ out) {
    int wid = threadIdx.x >> 6, lane = threadIdx.x & 63;
    int n = blockIdx.x * 4 + wid;
    if (n >= NN) return;
    float si = s2I[n], sjn = s2J[n];
    int c = lane < CLS ? lane : 0;
    float p = __expf(lrelu(si + sjn));
    float asum = p;
    float acc = fea2[(size_t)n * CLS + c] * p;
    int beg = row_off[n], end = row_off[n + 1];
    int e = beg;
    for (; e + 8 <= end; e += 8) {
        int s0 = csr[e + 0], s1 = csr[e + 1], s2 = csr[e + 2], s3 = csr[e + 3];
        int s4 = csr[e + 4], s5 = csr[e + 5], s6 = csr[e + 6], s7 = csr[e + 7];
        float a0 = s2J[s0], a1 = s2J[s1], a2 = s2J[s2], a3 = s2J[s3];
        float a4 = s2J[s4], a5 = s2J[s5], a6 = s2J[s6], a7 = s2J[s7];
        float f0 = fea2[(size_t)s0 * CLS + c];
        float f1 = fea2[(size_t)s1 * CLS + c];
        float f2 = fea2[(size_t)s2 * CLS + c];
        float f3 = fea2[(size_t)s3 * CLS + c];
        float f4 = fea2[(size_t)s4 * CLS + c];
        float f5 = fea2[(size_t)s5 * CLS + c];
        float f6 = fea2[(size_t)s6 * CLS + c];
        float f7 = fea2[(size_t)s7 * CLS + c];
        float p0 = __expf(lrelu(si + a0));
        float p1 = __expf(lrelu(si + a1));
        float p2 = __expf(lrelu(si + a2));
        float p3 = __expf(lrelu(si + a3));
        float p4 = __expf(lrelu(si + a4));
        float p5 = __expf(lrelu(si + a5));
        float p6 = __expf(lrelu(si + a6));
        float p7 = __expf(lrelu(si + a7));
        asum += ((p0 + p1) + (p2 + p3)) + ((p4 + p5) + (p6 + p7));
        acc += (f0 * p0 + f1 * p1 + f2 * p2 + f3 * p3)
             + (f4 * p4 + f5 * p5 + f6 * p6 + f7 * p7);
    }
    for (; e + 4 <= end; e += 4) {
        int s0 = csr[e], s1 = csr[e + 1], s2 = csr[e + 2], s3 = csr[e + 3];
        float p0 = __expf(lrelu(si + s2J[s0]));
        float p1 = __expf(lrelu(si + s2J[s1]));
        float p2 = __expf(lrelu(si + s2J[s2]));
        float p3 = __expf(lrelu(si + s2J[s3]));
        float f0 = fea2[(size_t)s0 * CLS + c];
        float f1 = fea2[(size_t)s1 * CLS + c];
        float f2 = fea2[(size_t)s2 * CLS + c];
        float f3 = fea2[(size_t)s3 * CLS + c];
        asum += (p0 + p1) + (p2 + p3);
        acc += f0 * p0 + f1 * p1 + f2 * p2 + f3 * p3;
    }
    for (; e < end; ++e) {
        int s = csr[e];
        float pe = __expf(lrelu(si + s2J[s]));
        asum += pe;
        acc += fea2[(size_t)s * CLS + c] * pe;
    }
    float row = acc / (asum + 1e-16f) + bias2[c];
    float v = (lane < CLS) ? row : -3.0e38f;
    float vm = v;
    #pragma unroll
    for (int off = 32; off; off >>= 1) vm = fmaxf(vm, __shfl_xor(vm, off));
    float ex = (lane < CLS) ? __expf(v - vm) : 0.f;
    float es = ex;
    #pragma unroll
    for (int off = 32; off; off >>= 1) es += __shfl_xor(es, off);
    if (lane < CLS) out[(size_t)n * CLS + lane] = ex / es;
}

extern "C" void kernel_launch(void* const* d_in, const int* in_sizes, int n_in,
                              void* d_out, int out_size, void* d_ws, size_t ws_size,
                              hipStream_t stream) {
    const float* x     = (const float*)d_in[0];
    const int*   ei    = (const int*)d_in[1];
    const float* w1    = (const float*)d_in[2];
    const float* b1    = (const float*)d_in[3];
    const float* att1  = (const float*)d_in[4];
    const float* bias1 = (const float*)d_in[5];
    const float* w2    = (const float*)d_in[6];
    const float* b2    = (const float*)d_in[7];
    const float* att2  = (const float*)d_in[8];
    const float* bias2 = (const float*)d_in[9];
    const int* src = ei;
    const int* dst = ei + NE;
    float* out = (float*)d_out;

    char* p = (char*)d_ws;
    auto alloc = [&](size_t bytes) {
        char* r = p;
        p += (bytes + 255) & ~(size_t)255;
        return r;
    };
    __half* fea1h = (__half*)alloc((size_t)NN * F1 * 2);
    float* h1     = (float*)alloc((size_t)NN * F1 * 4);
    float* sI1    = (float*)alloc((size_t)NN * 4 * 4);
    float* sJ1    = (float*)alloc((size_t)NN * 4 * 4);
    float* fea2   = (float*)alloc((size_t)NN * CLS * 4);
    float* s2I    = (float*)alloc((size_t)NN * 4);
    float* s2J    = (float*)alloc((size_t)NN * 4);
    int*   deg    = (int*)alloc((size_t)NN * 4);
    int*   row_off= (int*)alloc((size_t)(NN + 1) * 4);
    int*   bsum   = (int*)alloc((size_t)NB * 4);
    int*   bpref  = (int*)alloc((size_t)NB * 4);
    int*   ord    = (int*)alloc((size_t)NE * 4);
    int*   csr    = (int*)alloc((size_t)NE * 4);
    float* ep1    = (float*)alloc((size_t)NE * 4 * 4);

    hipMemsetAsync(deg, 0, (size_t)NN * 4, stream);

    dim3 g1((NN + BM - 1) / BM, F1 / BN);
    gemm1_k<<<g1, 256, 0, stream>>>(x, w1, b1, att1, fea1h, sI1, sJ1);
    hist_k<<<(NE + 255) / 256, 256, 0, stream>>>(dst, deg, ord);
    scan1_k<<<NB, 1024, 0, stream>>>(deg, row_off, bsum);
    scan2_k<<<1, 64, 0, stream>>>(bsum, bpref);
    scan3_k<<<NB, 1024, 0, stream>>>(row_off, bpref);
    scatter_k<<<(NE + 255) / 256, 256, 0, stream>>>(src, dst, ord, row_off,
                                                    sI1, sJ1, csr, (float4*)ep1);
    agg1_k<<<(NN + 3) / 4, 256, 0, stream>>>(fea1h, sI1, sJ1, ep1, row_off, csr, bias1, h1);
    gemm2_k<<<(NN + G2N - 1) / G2N, 256, 0, stream>>>(h1, w2, b2, att2, fea2, s2I, s2J);
    agg2_k<<<(NN + 3) / 4, 256, 0, stream>>>(fea2, s2I, s2J, row_off, csr, bias2, out);
}

// Round 10
// 257.942 us; speedup vs baseline: 1.2002x; 1.0016x over previous
//
#include <hip/hip_runtime.h>
#include <hip/hip_fp16.h>

#define NN 50000
#define NE 800000
#define INFEAT 128
#define F1 256
#define HID 64
#define CLS 40
#define NEGS 0.2f
#define NB 49   // ceil(NN / 1024)

__device__ __forceinline__ float lrelu(float x) { return x > 0.0f ? x : NEGS * x; }

struct alignas(8) H4 { __half2 a, b; };
struct alignas(16) H8 { __half2 a, b, c, d; };

// ---------------- GEMM1: fea1h = fp16(x @ W1 + b1), fused per-node scores ----------------
// 128x64 tile, 8x4 per thread; register-prefetch pipeline over K tiles
#define BM 128
#define BN 64
#define BK 32
__global__ __launch_bounds__(256) void gemm1_k(const float* __restrict__ A,
                                               const float* __restrict__ W,
                                               const float* __restrict__ b,
                                               const float* __restrict__ att1,
                                               __half* __restrict__ feah,
                                               float* __restrict__ sI,
                                               float* __restrict__ sJ) {
    __shared__ float As[BK][BM + 4];
    __shared__ float Bs[BK][BN];
    int tid = threadIdx.x;
    int row0 = blockIdx.x * BM;
    int head = blockIdx.y;          // BN==HID: one head per column block
    int col0 = head * BN;
    int tx = tid & 15, ty = tid >> 4;
    // staging indices
    int ar = tid >> 3;              // 0..31
    int ac = (tid & 7) * 4;         // 0..28
    int br = tid >> 4;              // 0..15
    int bc = (tid & 15) * 4;
    float4 pa[4], pb[2];
    auto load_tile = [&](int k0) {
        #pragma unroll
        for (int i = 0; i < 4; ++i) {
            int grow = row0 + ar + i * 32;
            pa[i] = (grow < NN) ? *(const float4*)&A[(size_t)grow * INFEAT + k0 + ac]
                                : make_float4(0.f, 0.f, 0.f, 0.f);
        }
        #pragma unroll
        for (int i = 0; i < 2; ++i)
            pb[i] = *(const float4*)&W[(size_t)(k0 + br + i * 16) * F1 + col0 + bc];
    };
    float acc[8][4] = {};
    load_tile(0);
    for (int k0 = 0; k0 < INFEAT; k0 += BK) {
        // write staged regs to LDS
        #pragma unroll
        for (int i = 0; i < 4; ++i) {
            int rr = ar + i * 32;
            As[ac + 0][rr] = pa[i].x; As[ac + 1][rr] = pa[i].y;
            As[ac + 2][rr] = pa[i].z; As[ac + 3][rr] = pa[i].w;
        }
        #pragma unroll
        for (int i = 0; i < 2; ++i)
            *(float4*)&Bs[br + i * 16][bc] = pb[i];
        __syncthreads();
        if (k0 + BK < INFEAT) load_tile(k0 + BK);   // overlap with compute
        #pragma unroll
        for (int k = 0; k < BK; ++k) {
            float4 a0 = *(const float4*)&As[k][ty * 8];
            float4 a1 = *(const float4*)&As[k][ty * 8 + 4];
            float4 bv = *(const float4*)&Bs[k][tx * 4];
            float a[8] = {a0.x, a0.y, a0.z, a0.w, a1.x, a1.y, a1.z, a1.w};
            float bb[4] = {bv.x, bv.y, bv.z, bv.w};
            #pragma unroll
            for (int i = 0; i < 8; ++i)
                #pragma unroll
                for (int j = 0; j < 4; ++j) acc[i][j] += a[i] * bb[j];
        }
        __syncthreads();
    }
    int gcol = col0 + tx * 4;
    float4 bv = *(const float4*)&b[gcol];
    float aI0 = att1[head * 2 * HID + tx * 4 + 0];
    float aI1 = att1[head * 2 * HID + tx * 4 + 1];
    float aI2 = att1[head * 2 * HID + tx * 4 + 2];
    float aI3 = att1[head * 2 * HID + tx * 4 + 3];
    float aJ0 = att1[head * 2 * HID + HID + tx * 4 + 0];
    float aJ1 = att1[head * 2 * HID + HID + tx * 4 + 1];
    float aJ2 = att1[head * 2 * HID + HID + tx * 4 + 2];
    float aJ3 = att1[head * 2 * HID + HID + tx * 4 + 3];
    float sIp[8], sJp[8];
    #pragma unroll
    for (int i = 0; i < 8; ++i) {
        float4 o = make_float4(acc[i][0] + bv.x, acc[i][1] + bv.y,
                               acc[i][2] + bv.z, acc[i][3] + bv.w);
        int grow = row0 + ty * 8 + i;
        if (grow < NN) {
            H4 v;
            v.a = __floats2half2_rn(o.x, o.y);
            v.b = __floats2half2_rn(o.z, o.w);
            *(H4*)&feah[(size_t)grow * F1 + gcol] = v;
        }
        sIp[i] = o.x * aI0 + o.y * aI1 + o.z * aI2 + o.w * aI3;
        sJp[i] = o.x * aJ0 + o.y * aJ1 + o.z * aJ2 + o.w * aJ3;
    }
    #pragma unroll
    for (int off = 1; off < 16; off <<= 1) {
        #pragma unroll
        for (int i = 0; i < 8; ++i) {
            sIp[i] += __shfl_xor(sIp[i], off);
            sJp[i] += __shfl_xor(sJp[i], off);
        }
    }
    if (tx == 0) {
        #pragma unroll
        for (int i = 0; i < 8; ++i) {
            int grow = row0 + ty * 8 + i;
            if (grow < NN) {
                sI[grow * 4 + head] = sIp[i];
                sJ[grow * 4 + head] = sJp[i];
            }
        }
    }
}

// ---------------- CSR build: histogram harvests the ordinal ----------------
__global__ void hist_k(const int* __restrict__ dst, int* __restrict__ deg,
                       int* __restrict__ ord) {
    int e = blockIdx.x * blockDim.x + threadIdx.x;
    if (e < NE) ord[e] = atomicAdd(&deg[dst[e]], 1);
}

// hierarchical scan: 49 blocks of 1024, then 1-wave scan of block sums, then add-back
__global__ __launch_bounds__(1024) void scan1_k(const int* __restrict__ deg,
                                                int* __restrict__ row_off,
                                                int* __restrict__ bsum) {
    __shared__ int tmp[1024];
    int tid = threadIdx.x;
    int gid = blockIdx.x * 1024 + tid;
    int v = (gid < NN) ? deg[gid] : 0;
    tmp[tid] = v;
    __syncthreads();
    #pragma unroll
    for (int off = 1; off < 1024; off <<= 1) {
        int t = (tid >= off) ? tmp[tid - off] : 0;
        __syncthreads();
        tmp[tid] += t;
        __syncthreads();
    }
    if (gid < NN) row_off[gid] = tmp[tid] - v;   // exclusive
    if (tid == 1023) bsum[blockIdx.x] = tmp[1023];
}

__global__ void scan2_k(const int* __restrict__ bsum, int* __restrict__ bpref) {
    int tid = threadIdx.x;           // 64 threads, one wave
    int orig = (tid < NB) ? bsum[tid] : 0;
    int v = orig;
    #pragma unroll
    for (int off = 1; off < 64; off <<= 1) {
        int t = __shfl_up(v, off);
        if (tid >= off) v += t;
    }
    if (tid < NB) bpref[tid] = v - orig;   // exclusive block prefix
}

__global__ __launch_bounds__(1024) void scan3_k(int* __restrict__ row_off,
                                                const int* __restrict__ bpref) {
    int gid = blockIdx.x * 1024 + threadIdx.x;
    if (gid < NN) row_off[gid] += bpref[blockIdx.x];
    if (gid == 0) row_off[NN] = NE;      // total degree is exactly NE
}

// ---------------- scatter: atomic-free (pos = row_off[dst] + ord), fused ep1 ----------------
__global__ void scatter_k(const int* __restrict__ src, const int* __restrict__ dst,
                          const int* __restrict__ ord, const int* __restrict__ row_off,
                          const float* __restrict__ sI, const float* __restrict__ sJ,
                          int* __restrict__ csr, float4* __restrict__ ep4) {
    int e = blockIdx.x * blockDim.x + threadIdx.x;
    if (e >= NE) return;
    int s = src[e], d = dst[e];
    int pos = row_off[d] + ord[e];
    float4 si = *(const float4*)&sI[d * 4];
    float4 sj = *(const float4*)&sJ[s * 4];
    float4 r;
    r.x = __expf(lrelu(si.x + sj.x));
    r.y = __expf(lrelu(si.y + sj.y));
    r.z = __expf(lrelu(si.z + sj.z));
    r.w = __expf(lrelu(si.w + sj.w));
    csr[pos] = s;
    ep4[pos] = r;
}

// ---------------- layer-1 aggregation: streams precomputed ep, fp16 row gathers ----------------
__global__ __launch_bounds__(256, 6) void agg1_k(const __half* __restrict__ feah,
                                                 const float* __restrict__ sI,
                                                 const float* __restrict__ sJ,
                                                 const float* __restrict__ epf,
                                                 const int* __restrict__ row_off,
                                                 const int* __restrict__ csr,
                                                 const float* __restrict__ bias,
                                                 float* __restrict__ out) {
    int wid = threadIdx.x >> 6, lane = threadIdx.x & 63;
    int n = blockIdx.x * 4 + wid;
    if (n >= NN) return;
    int h = lane >> 4;           // head of this lane's channels
    int c = lane * 4;            // channel group
    // self loop
    float p = __expf(lrelu(sI[n * 4 + h] + sJ[n * 4 + h]));
    float asum = p;
    H4 vs = *(const H4*)&feah[(size_t)n * F1 + c];
    float2 sx = __half22float2(vs.a), sy = __half22float2(vs.b);
    float4 acc = make_float4(sx.x * p, sx.y * p, sy.x * p, sy.y * p);
    int beg = row_off[n], end = row_off[n + 1];
    int e = beg;
    for (; e + 8 <= end; e += 8) {
        int s0 = csr[e + 0], s1 = csr[e + 1], s2 = csr[e + 2], s3 = csr[e + 3];
        int s4 = csr[e + 4], s5 = csr[e + 5], s6 = csr[e + 6], s7 = csr[e + 7];
        float p0 = epf[(e + 0) * 4 + h], p1 = epf[(e + 1) * 4 + h];
        float p2 = epf[(e + 2) * 4 + h], p3 = epf[(e + 3) * 4 + h];
        float p4 = epf[(e + 4) * 4 + h], p5 = epf[(e + 5) * 4 + h];
        float p6 = epf[(e + 6) * 4 + h], p7 = epf[(e + 7) * 4 + h];
        H4 v0 = *(const H4*)&feah[(size_t)s0 * F1 + c];
        H4 v1 = *(const H4*)&feah[(size_t)s1 * F1 + c];
        H4 v2 = *(const H4*)&feah[(size_t)s2 * F1 + c];
        H4 v3 = *(const H4*)&feah[(size_t)s3 * F1 + c];
        H4 v4 = *(const H4*)&feah[(size_t)s4 * F1 + c];
        H4 v5 = *(const H4*)&feah[(size_t)s5 * F1 + c];
        H4 v6 = *(const H4*)&feah[(size_t)s6 * F1 + c];
        H4 v7 = *(const H4*)&feah[(size_t)s7 * F1 + c];
        asum += ((p0 + p1) + (p2 + p3)) + ((p4 + p5) + (p6 + p7));
        float2 x0 = __half22float2(v0.a), y0 = __half22float2(v0.b);
        float2 x1 = __half22float2(v1.a), y1 = __half22float2(v1.b);
        float2 x2 = __half22float2(v2.a), y2 = __half22float2(v2.b);
        float2 x3 = __half22float2(v3.a), y3 = __half22float2(v3.b);
        float2 x4 = __half22float2(v4.a), y4 = __half22float2(v4.b);
        float2 x5 = __half22float2(v5.a), y5 = __half22float2(v5.b);
        float2 x6 = __half22float2(v6.a), y6 = __half22float2(v6.b);
        float2 x7 = __half22float2(v7.a), y7 = __half22float2(v7.b);
        acc.x += (x0.x * p0 + x1.x * p1 + x2.x * p2 + x3.x * p3)
               + (x4.x * p4 + x5.x * p5 + x6.x * p6 + x7.x * p7);
        acc.y += (x0.y * p0 + x1.y * p1 + x2.y * p2 + x3.y * p3)
               + (x4.y * p4 + x5.y * p5 + x6.y * p6 + x7.y * p7);
        acc.z += (y0.x * p0 + y1.x * p1 + y2.x * p2 + y3.x * p3)
               + (y4.x * p4 + y5.x * p5 + y6.x * p6 + y7.x * p7);
        acc.w += (y0.y * p0 + y1.y * p1 + y2.y * p2 + y3.y * p3)
               + (y4.y * p4 + y5.y * p5 + y6.y * p6 + y7.y * p7);
    }
    for (; e + 4 <= end; e += 4) {
        int s0 = csr[e], s1 = csr[e + 1], s2 = csr[e + 2], s3 = csr[e + 3];
        float p0 = epf[(e + 0) * 4 + h], p1 = epf[(e + 1) * 4 + h];
        float p2 = epf[(e + 2) * 4 + h], p3 = epf[(e + 3) * 4 + h];
        H4 v0 = *(const H4*)&feah[(size_t)s0 * F1 + c];
        H4 v1 = *(const H4*)&feah[(size_t)s1 * F1 + c];
        H4 v2 = *(const H4*)&feah[(size_t)s2 * F1 + c];
        H4 v3 = *(const H4*)&feah[(size_t)s3 * F1 + c];
        asum += (p0 + p1) + (p2 + p3);
        float2 x0 = __half22float2(v0.a), y0 = __half22float2(v0.b);
        float2 x1 = __half22float2(v1.a), y1 = __half22float2(v1.b);
        float2 x2 = __half22float2(v2.a), y2 = __half22float2(v2.b);
        float2 x3 = __half22float2(v3.a), y3 = __half22float2(v3.b);
        acc.x += x0.x * p0 + x1.x * p1 + x2.x * p2 + x3.x * p3;
        acc.y += x0.y * p0 + x1.y * p1 + x2.y * p2 + x3.y * p3;
        acc.z += y0.x * p0 + y1.x * p1 + y2.x * p2 + y3.x * p3;
        acc.w += y0.y * p0 + y1.y * p1 + y2.y * p2 + y3.y * p3;
    }
    for (; e < end; ++e) {
        int s = csr[e];
        float pe = epf[e * 4 + h];
        asum += pe;
        H4 v = *(const H4*)&feah[(size_t)s * F1 + c];
        float2 x = __half22float2(v.a), y = __half22float2(v.b);
        acc.x += x.x * pe; acc.y += x.y * pe;
        acc.z += y.x * pe; acc.w += y.y * pe;
    }
    float inv = 1.0f / (asum + 1e-16f);
    float4 bv = *(const float4*)&bias[c];
    float4 o;
    o.x = fmaxf(acc.x * inv + bv.x, 0.f);
    o.y = fmaxf(acc.y * inv + bv.y, 0.f);
    o.z = fmaxf(acc.z * inv + bv.z, 0.f);
    o.w = fmaxf(acc.w * inv + bv.w, 0.f);
    *(float4*)&out[(size_t)n * F1 + c] = o;
}

// ---------------- GEMM2: thread-per-(2 nodes, 8 classes), W2 staged once, fp16 fea2 out ----------------
#define G2N 102   // nodes per block: 51 pairs, 255 active threads
__global__ __launch_bounds__(256) void gemm2_k(const float* __restrict__ h1,
                                               const float* __restrict__ W2,
                                               const float* __restrict__ b2,
                                               const float* __restrict__ att2,
                                               __half* __restrict__ fea2h,
                                               float* __restrict__ s2I,
                                               float* __restrict__ s2J) {
    __shared__ float Ws[F1 * CLS];         // 40 KB
    __shared__ float redI[G2N][5];
    __shared__ float redJ[G2N][5];
    int tid = threadIdx.x;
    for (int i = tid * 4; i < F1 * CLS; i += 256 * 4)
        *(float4*)&Ws[i] = *(const float4*)&W2[i];
    __syncthreads();
    int nl = tid / 5, g = tid - nl * 5;    // nl 0..50, g 0..4
    int na = blockIdx.x * G2N + nl * 2;
    int nb = na + 1;
    bool actA = (tid < 255) && (na < NN);
    bool actB = (tid < 255) && (nb < NN);
    int c0 = g * 8;
    float accA[8] = {}, accB[8] = {};
    if (actA) {
        const float* rowA = h1 + (size_t)na * F1;
        const float* rowB = h1 + (size_t)(actB ? nb : na) * F1;
        for (int k = 0; k < F1; k += 4) {
            float4 ha = *(const float4*)&rowA[k];
            float4 hb = *(const float4*)&rowB[k];
            float a[4] = {ha.x, ha.y, ha.z, ha.w};
            float bl[4] = {hb.x, hb.y, hb.z, hb.w};
            #pragma unroll
            for (int kk = 0; kk < 4; ++kk) {
                float4 w0 = *(const float4*)&Ws[(k + kk) * CLS + c0];
                float4 w1 = *(const float4*)&Ws[(k + kk) * CLS + c0 + 4];
                accA[0] += a[kk] * w0.x; accA[1] += a[kk] * w0.y;
                accA[2] += a[kk] * w0.z; accA[3] += a[kk] * w0.w;
                accA[4] += a[kk] * w1.x; accA[5] += a[kk] * w1.y;
                accA[6] += a[kk] * w1.z; accA[7] += a[kk] * w1.w;
                accB[0] += bl[kk] * w0.x; accB[1] += bl[kk] * w0.y;
                accB[2] += bl[kk] * w0.z; accB[3] += bl[kk] * w0.w;
                accB[4] += bl[kk] * w1.x; accB[5] += bl[kk] * w1.y;
                accB[6] += bl[kk] * w1.z; accB[7] += bl[kk] * w1.w;
            }
        }
        float4 bb0 = *(const float4*)&b2[c0];
        float4 bb1 = *(const float4*)&b2[c0 + 4];
        float bias8[8] = {bb0.x, bb0.y, bb0.z, bb0.w, bb1.x, bb1.y, bb1.z, bb1.w};
        float sIa = 0.f, sJa = 0.f, sIb = 0.f, sJb = 0.f;
        #pragma unroll
        for (int j = 0; j < 8; ++j) {
            accA[j] += bias8[j];
            accB[j] += bias8[j];
            float aI = att2[c0 + j], aJ = att2[CLS + c0 + j];
            sIa += accA[j] * aI; sJa += accA[j] * aJ;
            sIb += accB[j] * aI; sJb += accB[j] * aJ;
        }
        H8 ha8;
        ha8.a = __floats2half2_rn(accA[0], accA[1]);
        ha8.b = __floats2half2_rn(accA[2], accA[3]);
        ha8.c = __floats2half2_rn(accA[4], accA[5]);
        ha8.d = __floats2half2_rn(accA[6], accA[7]);
        *(H8*)&fea2h[(size_t)na * CLS + c0] = ha8;
        redI[nl * 2][g] = sIa;
        redJ[nl * 2][g] = sJa;
        if (actB) {
            H8 hb8;
            hb8.a = __floats2half2_rn(accB[0], accB[1]);
            hb8.b = __floats2half2_rn(accB[2], accB[3]);
            hb8.c = __floats2half2_rn(accB[4], accB[5]);
            hb8.d = __floats2half2_rn(accB[6], accB[7]);
            *(H8*)&fea2h[(size_t)nb * CLS + c0] = hb8;
            redI[nl * 2 + 1][g] = sIb;
            redJ[nl * 2 + 1][g] = sJb;
        }
    }
    __syncthreads();
    if (actA && g == 0) {
        int r = nl * 2;
        s2I[na] = redI[r][0] + redI[r][1] + redI[r][2] + redI[r][3] + redI[r][4];
        s2J[na] = redJ[r][0] + redJ[r][1] + redJ[r][2] + redJ[r][3] + redJ[r][4];
        if (actB) {
            s2I[nb] = redI[r + 1][0] + redI[r + 1][1] + redI[r + 1][2] + redI[r + 1][3] + redI[r + 1][4];
            s2J[nb] = redJ[r + 1][0] + redJ[r + 1][1] + redJ[r + 1][2] + redJ[r + 1][3] + redJ[r + 1][4];
        }
    }
}

// ---------------- layer-2 aggregation + bias + row softmax (fp16 fea2 gathers) ----------------
__global__ __launch_bounds__(256) void agg2_k(const __half* __restrict__ fea2h,
                                              const float* __restrict__ s2I,
                                              const float* __restrict__ s2J,
                                              const int* __restrict__ row_off,
                                              const int* __restrict__ csr,
                                              const float* __restrict__ bias2,
                                              float* __restrict__ out) {
    int wid = threadIdx.x >> 6, lane = threadIdx.x & 63;
    int n = blockIdx.x * 4 + wid;
    if (n >= NN) return;
    float si = s2I[n], sjn = s2J[n];
    int c = lane < CLS ? lane : 0;
    float p = __expf(lrelu(si + sjn));
    float asum = p;
    float acc = __half2float(fea2h[(size_t)n * CLS + c]) * p;
    int beg = row_off[n], end = row_off[n + 1];
    int e = beg;
    for (; e + 8 <= end; e += 8) {
        int s0 = csr[e + 0], s1 = csr[e + 1], s2 = csr[e + 2], s3 = csr[e + 3];
        int s4 = csr[e + 4], s5 = csr[e + 5], s6 = csr[e + 6], s7 = csr[e + 7];
        float a0 = s2J[s0], a1 = s2J[s1], a2 = s2J[s2], a3 = s2J[s3];
        float a4 = s2J[s4], a5 = s2J[s5], a6 = s2J[s6], a7 = s2J[s7];
        __half f0 = fea2h[(size_t)s0 * CLS + c];
        __half f1 = fea2h[(size_t)s1 * CLS + c];
        __half f2 = fea2h[(size_t)s2 * CLS + c];
        __half f3 = fea2h[(size_t)s3 * CLS + c];
        __half f4 = fea2h[(size_t)s4 * CLS + c];
        __half f5 = fea2h[(size_t)s5 * CLS + c];
        __half f6 = fea2h[(size_t)s6 * CLS + c];
        __half f7 = fea2h[(size_t)s7 * CLS + c];
        float p0 = __expf(lrelu(si + a0));
        float p1 = __expf(lrelu(si + a1));
        float p2 = __expf(lrelu(si + a2));
        float p3 = __expf(lrelu(si + a3));
        float p4 = __expf(lrelu(si + a4));
        float p5 = __expf(lrelu(si + a5));
        float p6 = __expf(lrelu(si + a6));
        float p7 = __expf(lrelu(si + a7));
        asum += ((p0 + p1) + (p2 + p3)) + ((p4 + p5) + (p6 + p7));
        acc += (__half2float(f0) * p0 + __half2float(f1) * p1
              + __half2float(f2) * p2 + __half2float(f3) * p3)
             + (__half2float(f4) * p4 + __half2float(f5) * p5
              + __half2float(f6) * p6 + __half2float(f7) * p7);
    }
    for (; e + 4 <= end; e += 4) {
        int s0 = csr[e], s1 = csr[e + 1], s2 = csr[e + 2], s3 = csr[e + 3];
        float p0 = __expf(lrelu(si + s2J[s0]));
        float p1 = __expf(lrelu(si + s2J[s1]));
        float p2 = __expf(lrelu(si + s2J[s2]));
        float p3 = __expf(lrelu(si + s2J[s3]));
        __half f0 = fea2h[(size_t)s0 * CLS + c];
        __half f1 = fea2h[(size_t)s1 * CLS + c];
        __half f2 = fea2h[(size_t)s2 * CLS + c];
        __half f3 = fea2h[(size_t)s3 * CLS + c];
        asum += (p0 + p1) + (p2 + p3);
        acc += __half2float(f0) * p0 + __half2float(f1) * p1
             + __half2float(f2) * p2 + __half2float(f3) * p3;
    }
    for (; e < end; ++e) {
        int s = csr[e];
        float pe = __expf(lrelu(si + s2J[s]));
        asum += pe;
        acc += __half2float(fea2h[(size_t)s * CLS + c]) * pe;
    }
    float row = acc / (asum + 1e-16f) + bias2[c];
    float v = (lane < CLS) ? row : -3.0e38f;
    float vm = v;
    #pragma unroll
    for (int off = 32; off; off >>= 1) vm = fmaxf(vm, __shfl_xor(vm, off));
    float ex = (lane < CLS) ? __expf(v - vm) : 0.f;
    float es = ex;
    #pragma unroll
    for (int off = 32; off; off >>= 1) es += __shfl_xor(es, off);
    if (lane < CLS) out[(size_t)n * CLS + lane] = ex / es;
}

extern "C" void kernel_launch(void* const* d_in, const int* in_sizes, int n_in,
                              void* d_out, int out_size, void* d_ws, size_t ws_size,
                              hipStream_t stream) {
    const float* x     = (const float*)d_in[0];
    const int*   ei    = (const int*)d_in[1];
    const float* w1    = (const float*)d_in[2];
    const float* b1    = (const float*)d_in[3];
    const float* att1  = (const float*)d_in[4];
    const float* bias1 = (const float*)d_in[5];
    const float* w2    = (const float*)d_in[6];
    const float* b2    = (const float*)d_in[7];
    const float* att2  = (const float*)d_in[8];
    const float* bias2 = (const float*)d_in[9];
    const int* src = ei;
    const int* dst = ei + NE;
    float* out = (float*)d_out;

    char* p = (char*)d_ws;
    auto alloc = [&](size_t bytes) {
        char* r = p;
        p += (bytes + 255) & ~(size_t)255;
        return r;
    };
    __half* fea1h = (__half*)alloc((size_t)NN * F1 * 2);
    float* h1     = (float*)alloc((size_t)NN * F1 * 4);
    float* sI1    = (float*)alloc((size_t)NN * 4 * 4);
    float* sJ1    = (float*)alloc((size_t)NN * 4 * 4);
    __half* fea2h = (__half*)alloc((size_t)NN * CLS * 2);
    float* s2I    = (float*)alloc((size_t)NN * 4);
    float* s2J    = (float*)alloc((size_t)NN * 4);
    int*   deg    = (int*)alloc((size_t)NN * 4);
    int*   row_off= (int*)alloc((size_t)(NN + 1) * 4);
    int*   bsum   = (int*)alloc((size_t)NB * 4);
    int*   bpref  = (int*)alloc((size_t)NB * 4);
    int*   ord    = (int*)alloc((size_t)NE * 4);
    int*   csr    = (int*)alloc((size_t)NE * 4);
    float* ep1    = (float*)alloc((size_t)NE * 4 * 4);

    hipMemsetAsync(deg, 0, (size_t)NN * 4, stream);

    dim3 g1((NN + BM - 1) / BM, F1 / BN);
    gemm1_k<<<g1, 256, 0, stream>>>(x, w1, b1, att1, fea1h, sI1, sJ1);
    hist_k<<<(NE + 255) / 256, 256, 0, stream>>>(dst, deg, ord);
    scan1_k<<<NB, 1024, 0, stream>>>(deg, row_off, bsum);
    scan2_k<<<1, 64, 0, stream>>>(bsum, bpref);
    scan3_k<<<NB, 1024, 0, stream>>>(row_off, bpref);
    scatter_k<<<(NE + 255) / 256, 256, 0, stream>>>(src, dst, ord, row_off,
                                                    sI1, sJ1, csr, (float4*)ep1);
    agg1_k<<<(NN + 3) / 4, 256, 0, stream>>>(fea1h, sI1, sJ1, ep1, row_off, csr, bias1, h1);
    gemm2_k<<<(NN + G2N - 1) / G2N, 256, 0, stream>>>(h1, w2, b2, att2, fea2h, s2I, s2J);
    agg2_k<<<(NN + 3) / 4, 256, 0, stream>>>(fea2h, s2I, s2J, row_off, csr, bias2, out);
}